// Round 1
// baseline (391.756 us; speedup 1.0000x reference)
//
#include <hip/hip_runtime.h>

#define N_B   16
#define C_IN  32
#define C_OUT 32
#define H_IN  256
#define W_IN  256
#define H_OUT 254
#define W_OUT 254

#define TILE_X 32
#define TILE_Y 8
#define CI_CHUNK 8
#define N_CHUNKS 4          // 32 ci / 8

#define LDS_WPAD 12         // 9 taps padded to 12 floats (48B, 16B-aligned)
#define IN_ROWS  (TILE_Y + 2)   // 10
#define IN_COLS  (TILE_X + 2)   // 34
#define IN_PITCH 36             // padded pitch: balanced banks for b128 reads

__global__ __launch_bounds__(256, 2)
void conv3x3_f32(const float* __restrict__ x,
                 const float* __restrict__ w,
                 float* __restrict__ out) {
    __shared__ float w_lds[C_IN * C_OUT * LDS_WPAD];            // 49152 B
    __shared__ float in_lds[CI_CHUNK * IN_ROWS * IN_PITCH];     // 11520 B

    const int tid = threadIdx.x;
    const int b   = blockIdx.x;
    const int n   = b >> 8;          // 256 tiles per image
    const int rem = b & 255;
    const int ty  = rem >> 3;        // 32 y-tiles
    const int tx  = rem & 7;         // 8 x-tiles
    const int ty0 = ty * TILE_Y;
    const int tx0 = tx * TILE_X;

    const int wave    = tid >> 6;    // 4 waves, 8 co each
    const int lane    = tid & 63;
    const int co_base = wave * 8;
    const int sx      = lane & 7;    // 8 x-slots of 4 px
    const int sy      = lane >> 3;   // 8 y rows

    // ---- stage all weights: global [co][ci][3][3] -> lds [(ci*32+co)*12 + tap]
    for (int idx = tid; idx < C_OUT * C_IN * 9; idx += 256) {
        int co  = idx / (C_IN * 9);
        int r   = idx - co * (C_IN * 9);
        int ci  = r / 9;
        int tap = r - ci * 9;
        w_lds[(ci * C_OUT + co) * LDS_WPAD + tap] = w[idx];
    }

    float acc[8][4];
    #pragma unroll
    for (int i = 0; i < 8; ++i)
        #pragma unroll
        for (int j = 0; j < 4; ++j) acc[i][j] = 0.f;

    const int xn = n * (C_IN * H_IN * W_IN);

    for (int h = 0; h < N_CHUNKS; ++h) {
        if (h > 0) __syncthreads();          // previous chunk's readers done
        // ---- stage input chunk: 8 ci x 10 rows x 34 cols (zero-pad OOB halo)
        for (int idx = tid; idx < CI_CHUNK * IN_ROWS * IN_COLS; idx += 256) {
            int cc  = idx / (IN_ROWS * IN_COLS);
            int r2  = idx - cc * (IN_ROWS * IN_COLS);
            int row = r2 / IN_COLS;
            int col = r2 - row * IN_COLS;
            int ci  = h * CI_CHUNK + cc;
            int iy  = ty0 + row;
            int ix  = tx0 + col;
            float v = 0.f;
            if (iy < H_IN && ix < W_IN)
                v = x[xn + ci * (H_IN * W_IN) + iy * W_IN + ix];
            in_lds[(cc * IN_ROWS + row) * IN_PITCH + col] = v;
        }
        __syncthreads();

        #pragma unroll 2
        for (int cc = 0; cc < CI_CHUNK; ++cc) {
            const int ci = h * CI_CHUNK + cc;
            // ---- input registers: 3 rows x 8 cols (two aligned b128 per row)
            float rin[3][8];
            const int ibase = (cc * IN_ROWS + sy) * IN_PITCH + sx * 4;
            #pragma unroll
            for (int ky = 0; ky < 3; ++ky) {
                const float4 a  = *reinterpret_cast<const float4*>(&in_lds[ibase + ky * IN_PITCH]);
                const float4 b4 = *reinterpret_cast<const float4*>(&in_lds[ibase + ky * IN_PITCH + 4]);
                rin[ky][0] = a.x;  rin[ky][1] = a.y;  rin[ky][2] = a.z;  rin[ky][3] = a.w;
                rin[ky][4] = b4.x; rin[ky][5] = b4.y; rin[ky][6] = b4.z; rin[ky][7] = b4.w;
            }
            #pragma unroll
            for (int co = 0; co < 8; ++co) {
                // broadcast (wave-uniform) weight reads: conflict-free
                const float* wp = &w_lds[(ci * C_OUT + co_base + co) * LDS_WPAD];
                const float4 w0 = *reinterpret_cast<const float4*>(wp);
                const float4 w1 = *reinterpret_cast<const float4*>(wp + 4);
                const float  w8 = wp[8];
                const float wv[9] = {w0.x, w0.y, w0.z, w0.w, w1.x, w1.y, w1.z, w1.w, w8};
                #pragma unroll
                for (int ky = 0; ky < 3; ++ky)
                    #pragma unroll
                    for (int kx = 0; kx < 3; ++kx) {
                        const float wt = wv[ky * 3 + kx];
                        #pragma unroll
                        for (int p = 0; p < 4; ++p)
                            acc[co][p] = fmaf(rin[ky][p + kx], wt, acc[co][p]);
                    }
            }
        }
    }

    // ---- epilogue: scalar stores (row stride 254 breaks vector alignment)
    const int oy = ty0 + sy;
    if (oy < H_OUT) {
        #pragma unroll
        for (int co = 0; co < 8; ++co) {
            const int oc = co_base + co;
            float* op = out + ((size_t)(n * C_OUT + oc) * H_OUT + oy) * W_OUT;
            #pragma unroll
            for (int p = 0; p < 4; ++p) {
                const int ox = tx0 + sx * 4 + p;
                if (ox < W_OUT) op[ox] = acc[co][p];
            }
        }
    }
}

extern "C" void kernel_launch(void* const* d_in, const int* in_sizes, int n_in,
                              void* d_out, int out_size, void* d_ws, size_t ws_size,
                              hipStream_t stream) {
    const float* x = (const float*)d_in[0];
    const float* w = (const float*)d_in[1];
    float* out     = (float*)d_out;

    dim3 grid(N_B * 256);   // 16 images x (32 y-tiles * 8 x-tiles)
    dim3 block(256);
    hipLaunchKernelGGL(conv3x3_f32, grid, block, 0, stream, x, w, out);
}

// Round 2
// 151.915 us; speedup vs baseline: 2.5788x; 2.5788x over previous
//
#include <hip/hip_runtime.h>

#define N_B   16
#define C_IN  32
#define C_OUT 32
#define H_IN  256
#define W_IN  256
#define H_OUT 254
#define W_OUT 254

// block tile: 8 output rows x 64 output cols, all 32 co, all 32 ci (K=32, one shot)
#define ROWS_OUT 8
#define XT_OUT   64
#define IN_ROWS  10          // 8 + 2 halo
#define IN_COLS  66          // 64 + 2 halo

typedef __attribute__((ext_vector_type(8))) short bf16x8;
typedef __attribute__((ext_vector_type(4))) float f32x4;

__device__ __forceinline__ unsigned short f2bf(float f) {
    unsigned int u = __float_as_uint(f);
    unsigned int r = (u + 0x7FFFu + ((u >> 16) & 1u)) >> 16;   // RNE
    return (unsigned short)r;
}

__global__ __launch_bounds__(256, 2)
void conv3x3_mfma(const float* __restrict__ x,
                  const float* __restrict__ w,
                  float* __restrict__ out) {
    // weights: [tap][co][ci] bf16 (B-operand layout: ci contiguous per co)
    __shared__ unsigned short w_lds[9 * C_OUT * C_IN];                 // 18432 B
    // input tile: [row][col][ci] bf16, ci innermost (64 B / pixel), chunk-XOR swizzled
    __shared__ unsigned short in_lds[IN_ROWS * IN_COLS * C_IN];        // 42240 B

    const int tid  = threadIdx.x;
    const int b    = blockIdx.x;
    const int n    = b >> 7;          // 128 tiles per image
    const int rem  = b & 127;
    const int yt   = rem >> 2;        // 32 y-tiles
    const int xt   = rem & 3;         // 4 x-tiles
    const int y0   = yt * ROWS_OUT;
    const int x0   = xt * XT_OUT;

    const int wave = tid >> 6;
    const int lane = tid & 63;
    const int l15  = lane & 15;
    const int g    = lane >> 4;       // k-chunk / pixel-quad group

    // ---- stage weights -> LDS [tap][co][ci] (once; small, L2-cached globally)
    for (int i = tid; i < 9 * C_OUT * C_IN; i += 256) {
        const int co  = i / 288;          // global layout co*288 + ci*9 + tap
        const int r   = i - co * 288;
        const int ci  = r / 9;
        const int tap = r - ci * 9;
        w_lds[(tap * C_OUT + co) * C_IN + ci] = f2bf(w[i]);
    }
    __syncthreads();

    // ---- weight B-fragments -> registers: wf[tap][half]; lane: co = h*16+l15, ci = 8g..8g+7
    bf16x8 wf[9][2];
    #pragma unroll
    for (int tap = 0; tap < 9; ++tap)
        #pragma unroll
        for (int h = 0; h < 2; ++h) {
            const int off = (tap * C_OUT + h * 16 + l15) * C_IN + g * 8;
            wf[tap][h] = *reinterpret_cast<const bf16x8*>(&w_lds[off]);
        }

    // ---- stage input tile: transpose NCHW -> [row][col][ci] bf16
    // item = (chunk, row, col); col fastest => coalesced 4B x 64-lane global reads
    const float* xn = x + ((size_t)n << 21);
    for (int it = tid; it < 4 * IN_ROWS * IN_COLS; it += 256) {
        const int col = it % IN_COLS;
        const int t2  = it / IN_COLS;
        const int row = t2 % IN_ROWS;
        const int ch  = t2 / IN_ROWS;        // ci chunk of 8
        const int iy  = y0 + row;
        const int ix  = x0 + col;
        const bool inb = (iy < H_IN) && (ix < W_IN);
        const float* src = xn + ((size_t)(ch * 8) << 16) + (iy << 8) + ix;
        bf16x8 pk;
        #pragma unroll
        for (int c = 0; c < 8; ++c)
            pk[c] = inb ? (short)f2bf(src[(size_t)c << 16]) : (short)0;
        const int p   = row * IN_COLS + col;
        const int swz = ch ^ ((p >> 1) & 3);
        *reinterpret_cast<bf16x8*>(&in_lds[p * C_IN + swz * 8]) = pk;
    }
    __syncthreads();

    // ---- MFMA main: wave handles rows 2w, 2w+1; 4 x-subtiles of 16 px; 2 co halves
    f32x4 acc[2][4][2];
    #pragma unroll
    for (int r2 = 0; r2 < 2; ++r2)
        #pragma unroll
        for (int s = 0; s < 4; ++s)
            #pragma unroll
            for (int h = 0; h < 2; ++h) {
                f32x4 z = {0.f, 0.f, 0.f, 0.f};
                acc[r2][s][h] = z;
            }

    #pragma unroll
    for (int ky = 0; ky < 3; ++ky)
        #pragma unroll
        for (int kx = 0; kx < 3; ++kx) {
            const int tap = ky * 3 + kx;
            #pragma unroll
            for (int r2 = 0; r2 < 2; ++r2) {
                const int irow = 2 * wave + r2 + ky;
                #pragma unroll
                for (int s = 0; s < 4; ++s) {
                    // A-frag: pixel = l15 within subtile, k = ci 8g..8g+7
                    const int p    = irow * IN_COLS + s * 16 + kx + l15;
                    const int swz  = g ^ ((p >> 1) & 3);
                    const bf16x8 a = *reinterpret_cast<const bf16x8*>(&in_lds[p * C_IN + swz * 8]);
                    acc[r2][s][0] = __builtin_amdgcn_mfma_f32_16x16x32_bf16(a, wf[tap][0], acc[r2][s][0], 0, 0, 0);
                    acc[r2][s][1] = __builtin_amdgcn_mfma_f32_16x16x32_bf16(a, wf[tap][1], acc[r2][s][1], 0, 0, 0);
                }
            }
        }

    // ---- store: D lane layout: col = l15 = co-in-half, rows = pixels 4g..4g+3
    #pragma unroll
    for (int r2 = 0; r2 < 2; ++r2) {
        const int y = y0 + 2 * wave + r2;
        if (y >= H_OUT) continue;
        #pragma unroll
        for (int s = 0; s < 4; ++s) {
            const int xo = x0 + s * 16 + 4 * g;
            #pragma unroll
            for (int h = 0; h < 2; ++h) {
                const int co = h * 16 + l15;
                float* op = out + (size_t)(n * C_OUT + co) * (H_OUT * W_OUT) + y * W_OUT + xo;
                const f32x4 v = acc[r2][s][h];
                if (xo + 3 < W_OUT) {          // 8B-aligned (xo mult of 4, row base even)
                    *reinterpret_cast<float2*>(op)     = make_float2(v[0], v[1]);
                    *reinterpret_cast<float2*>(op + 2) = make_float2(v[2], v[3]);
                } else {
                    #pragma unroll
                    for (int q = 0; q < 4; ++q)
                        if (xo + q < W_OUT) op[q] = v[q];
                }
            }
        }
    }
}

extern "C" void kernel_launch(void* const* d_in, const int* in_sizes, int n_in,
                              void* d_out, int out_size, void* d_ws, size_t ws_size,
                              hipStream_t stream) {
    const float* x = (const float*)d_in[0];
    const float* w = (const float*)d_in[1];
    float* out     = (float*)d_out;

    dim3 grid(N_B * 128);   // 16 n * 32 y-tiles * 4 x-tiles = 2048
    dim3 block(256);
    hipLaunchKernelGGL(conv3x3_mfma, grid, block, 0, stream, x, w, out);
}

// Round 3
// 118.088 us; speedup vs baseline: 3.3175x; 1.2865x over previous
//
#include <hip/hip_runtime.h>

#define N_B   16
#define C_IN  32
#define C_OUT 32
#define H_IN  256
#define W_IN  256
#define H_OUT 254
#define W_OUT 254

typedef __attribute__((ext_vector_type(8))) short bf16x8;
typedef __attribute__((ext_vector_type(4))) float f32x4;

__device__ __forceinline__ unsigned short f2bf(float f) {
    unsigned int u = __float_as_uint(f);
    unsigned int r = (u + 0x7FFFu + ((u >> 16) & 1u)) >> 16;   // RNE
    return (unsigned short)r;
}

// ---------------------------------------------------------------- K0: pack W
// w[co][ci][ky][kx] fp32  ->  wT[tap][co][ci] bf16 (18432 B)
__global__ void k0_packw(const float* __restrict__ w, unsigned short* __restrict__ wT) {
    for (int i = threadIdx.x; i < C_OUT * C_IN * 9; i += 256) {
        const int co  = i / 288;
        const int r   = i - co * 288;
        const int ci  = r / 9;
        const int tap = r - ci * 9;
        wT[(tap * C_OUT + co) * C_IN + ci] = f2bf(w[i]);
    }
}

// ---------------------------------------------------------- K1: NCHW -> NHWC
// x[n][ci][y][col] fp32 -> xT[n][y][col][ci] bf16. One block per (n,y) row.
// LDS row[col][ci2-word] with XOR swizzle (ci2 ^ ((col>>1)&15)): write phase is
// bank-conflict-free (64 lanes cover all 32 banks exactly twice).
__global__ __launch_bounds__(256) void k1_tr(const float* __restrict__ x,
                                             unsigned int* __restrict__ xT) {
    __shared__ unsigned int row[4096];     // 16 KB = 256 col x 16 words(=32 ci)
    const int tid = threadIdx.x;
    const int b   = blockIdx.x;            // n*256 + y
    const float* src = x + (((size_t)(b >> 8)) << 21) + ((size_t)(b & 255) << 8);

    #pragma unroll
    for (int k = 0; k < 16; ++k) {
        const int id  = tid + (k << 8);
        const int col = id & 255;
        const int ci2 = id >> 8;           // pair of ci planes
        const float a = src[((size_t)ci2 << 17) + col];
        const float c = src[((size_t)ci2 << 17) + 65536 + col];
        row[(col << 4) | (ci2 ^ ((col >> 1) & 15))] =
            (unsigned)f2bf(a) | ((unsigned)f2bf(c) << 16);
    }
    __syncthreads();

    uint4* dst = (uint4*)(xT + ((size_t)b << 12));   // 16 KB per (n,y) row
    #pragma unroll
    for (int k = 0; k < 4; ++k) {
        const int id  = tid + (k << 8);    // 16B output chunk index
        const int col = id >> 2;
        const int c4  = id & 3;
        const int m   = (col >> 1) & 15;
        uint4 v;
        v.x = row[(col << 4) | (((c4 << 2) | 0) ^ m)];
        v.y = row[(col << 4) | (((c4 << 2) | 1) ^ m)];
        v.z = row[(col << 4) | (((c4 << 2) | 2) ^ m)];
        v.w = row[(col << 4) | (((c4 << 2) | 3) ^ m)];
        dst[id] = v;
    }
}

// ----------------------------------------------------------------- K2: conv
// No LDS, no barriers. Wave = 2 output rows x 64 cols, all 32 co.
// A-frags: direct global b128 from NHWC (1KB coalesced per instr, L1/L2 reuse
// across taps). Row-position loop P: frags of row R+P feed tap P (row R) and
// tap P-1 (row R+1). Weight frags direct from wT.
__global__ __launch_bounds__(256, 3)
void k2_conv(const unsigned short* __restrict__ xT,
             const unsigned short* __restrict__ wT,
             float* __restrict__ out) {
    const int tid  = threadIdx.x;
    const int bid  = blockIdx.x;
    // XCD swizzle inverse (grid 1024 = 8*128): orig-consecutive groups of 8
    // (same rows, adjacent strips/rblocks) land on the same XCD.
    const int o    = ((bid & 127) << 3) | (bid >> 7);
    const int n    = o >> 6;
    const int rr   = o & 63;
    const int rb   = rr >> 2;              // 16-row block
    const int x0   = (rr & 3) << 6;        // strip * 64
    const int wave = tid >> 6;
    const int lane = tid & 63;
    const int l15  = lane & 15;
    const int g    = lane >> 4;

    const char* xbase = (const char*)xT
        + (((size_t)((n << 8) + (rb << 4))) << 14)     // row (n*256 + rb*16)
        + ((x0 + l15) << 6) + (g << 4);
    const char* wbase = (const char*)wT + (((l15 << 5) + (g << 3)) << 1);

    #pragma unroll
    for (int q = 0; q < 2; ++q) {
        const int pr = wave + (q << 2);            // pair 0..7
        const int R  = (rb << 4) + (pr << 1);      // output row base (even)
        if (R >= H_OUT) continue;                  // edge pairs at rb=15

        f32x4 acc[2][4][2];
        #pragma unroll
        for (int r2 = 0; r2 < 2; ++r2)
            #pragma unroll
            for (int s = 0; s < 4; ++s)
                #pragma unroll
                for (int h = 0; h < 2; ++h) {
                    f32x4 z = {0.f, 0.f, 0.f, 0.f};
                    acc[r2][s][h] = z;
                }

        const char* prow = xbase + ((size_t)(pr << 1) << 14);
        bf16x8 wprev[3][2], wcur[3][2];

        #pragma unroll
        for (int P = 0; P < 4; ++P) {
            if (P <= 2) {
                #pragma unroll
                for (int kx = 0; kx < 3; ++kx)
                    #pragma unroll
                    for (int h = 0; h < 2; ++h)
                        wcur[kx][h] = *(const bf16x8*)(wbase + ((3 * P + kx) << 11) + (h << 10));
            }
            const char* arow = prow + ((size_t)P << 14);
            #pragma unroll
            for (int s = 0; s < 4; ++s) {
                const bf16x8 a0 = *(const bf16x8*)(arow + ((s << 4) + 0) * 64);
                const bf16x8 a1 = *(const bf16x8*)(arow + ((s << 4) + 1) * 64);
                const bf16x8 a2 = *(const bf16x8*)(arow + ((s << 4) + 2) * 64);
                if (P <= 2) {
                    #pragma unroll
                    for (int h = 0; h < 2; ++h) {
                        acc[0][s][h] = __builtin_amdgcn_mfma_f32_16x16x32_bf16(a0, wcur[0][h], acc[0][s][h], 0, 0, 0);
                        acc[0][s][h] = __builtin_amdgcn_mfma_f32_16x16x32_bf16(a1, wcur[1][h], acc[0][s][h], 0, 0, 0);
                        acc[0][s][h] = __builtin_amdgcn_mfma_f32_16x16x32_bf16(a2, wcur[2][h], acc[0][s][h], 0, 0, 0);
                    }
                }
                if (P >= 1) {
                    #pragma unroll
                    for (int h = 0; h < 2; ++h) {
                        acc[1][s][h] = __builtin_amdgcn_mfma_f32_16x16x32_bf16(a0, wprev[0][h], acc[1][s][h], 0, 0, 0);
                        acc[1][s][h] = __builtin_amdgcn_mfma_f32_16x16x32_bf16(a1, wprev[1][h], acc[1][s][h], 0, 0, 0);
                        acc[1][s][h] = __builtin_amdgcn_mfma_f32_16x16x32_bf16(a2, wprev[2][h], acc[1][s][h], 0, 0, 0);
                    }
                }
            }
            #pragma unroll
            for (int kx = 0; kx < 3; ++kx)
                #pragma unroll
                for (int h = 0; h < 2; ++h)
                    wprev[kx][h] = wcur[kx][h];     // SSA-renamed, no movs
        }

        // store: D row = pixel 4g+q', col = co = h*16+l15
        #pragma unroll
        for (int r2 = 0; r2 < 2; ++r2) {
            const int y = R + r2;                   // always < 254 (R even <=252)
            #pragma unroll
            for (int h = 0; h < 2; ++h) {
                const int co = (h << 4) | l15;
                float* op = out + (size_t)((n << 5) + co) * (H_OUT * W_OUT)
                          + y * W_OUT + x0 + (g << 2);
                #pragma unroll
                for (int s = 0; s < 4; ++s) {
                    const int xo = x0 + (s << 4) + (g << 2);
                    const f32x4 v = acc[r2][s][h];
                    float* p = op + (s << 4);
                    if (xo + 3 < W_OUT) {
                        *(float2*)p       = make_float2(v[0], v[1]);
                        *(float2*)(p + 2) = make_float2(v[2], v[3]);
                    } else if (xo + 1 < W_OUT) {    // xo==252 tail
                        *(float2*)p       = make_float2(v[0], v[1]);
                    }
                }
            }
        }
    }
}

// -------------------------------------------------- fallback (R1, verified)
#define ROWS_OUT 8
#define XT_OUT   64
#define IN_ROWS  10
#define IN_COLS  66

__global__ __launch_bounds__(256, 2)
void conv3x3_mfma(const float* __restrict__ x,
                  const float* __restrict__ w,
                  float* __restrict__ out) {
    __shared__ unsigned short w_lds[9 * C_OUT * C_IN];
    __shared__ unsigned short in_lds[IN_ROWS * IN_COLS * C_IN];

    const int tid  = threadIdx.x;
    const int b    = blockIdx.x;
    const int n    = b >> 7;
    const int rem  = b & 127;
    const int yt   = rem >> 2;
    const int xt   = rem & 3;
    const int y0   = yt * ROWS_OUT;
    const int x0   = xt * XT_OUT;
    const int wave = tid >> 6;
    const int lane = tid & 63;
    const int l15  = lane & 15;
    const int g    = lane >> 4;

    for (int i = tid; i < 9 * C_OUT * C_IN; i += 256) {
        const int co  = i / 288;
        const int r   = i - co * 288;
        const int ci  = r / 9;
        const int tap = r - ci * 9;
        w_lds[(tap * C_OUT + co) * C_IN + ci] = f2bf(w[i]);
    }
    __syncthreads();

    bf16x8 wf[9][2];
    #pragma unroll
    for (int tap = 0; tap < 9; ++tap)
        #pragma unroll
        for (int h = 0; h < 2; ++h)
            wf[tap][h] = *reinterpret_cast<const bf16x8*>(&w_lds[(tap * C_OUT + h * 16 + l15) * C_IN + g * 8]);

    const float* xn = x + ((size_t)n << 21);
    for (int it = tid; it < 4 * IN_ROWS * IN_COLS; it += 256) {
        const int col = it % IN_COLS;
        const int t2  = it / IN_COLS;
        const int row = t2 % IN_ROWS;
        const int ch  = t2 / IN_ROWS;
        const int iy  = y0 + row;
        const int ix  = x0 + col;
        const bool inb = (iy < H_IN) && (ix < W_IN);
        const float* src = xn + ((size_t)(ch * 8) << 16) + (iy << 8) + ix;
        bf16x8 pk;
        #pragma unroll
        for (int c = 0; c < 8; ++c)
            pk[c] = inb ? (short)f2bf(src[(size_t)c << 16]) : (short)0;
        const int p   = row * IN_COLS + col;
        const int swz = ch ^ ((p >> 1) & 3);
        *reinterpret_cast<bf16x8*>(&in_lds[p * C_IN + swz * 8]) = pk;
    }
    __syncthreads();

    f32x4 acc[2][4][2];
    #pragma unroll
    for (int r2 = 0; r2 < 2; ++r2)
        #pragma unroll
        for (int s = 0; s < 4; ++s)
            #pragma unroll
            for (int h = 0; h < 2; ++h) {
                f32x4 z = {0.f, 0.f, 0.f, 0.f};
                acc[r2][s][h] = z;
            }

    #pragma unroll
    for (int ky = 0; ky < 3; ++ky)
        #pragma unroll
        for (int kx = 0; kx < 3; ++kx) {
            const int tap = ky * 3 + kx;
            #pragma unroll
            for (int r2 = 0; r2 < 2; ++r2) {
                const int irow = 2 * wave + r2 + ky;
                #pragma unroll
                for (int s = 0; s < 4; ++s) {
                    const int p    = irow * IN_COLS + s * 16 + kx + l15;
                    const int swz  = g ^ ((p >> 1) & 3);
                    const bf16x8 a = *reinterpret_cast<const bf16x8*>(&in_lds[p * C_IN + swz * 8]);
                    acc[r2][s][0] = __builtin_amdgcn_mfma_f32_16x16x32_bf16(a, wf[tap][0], acc[r2][s][0], 0, 0, 0);
                    acc[r2][s][1] = __builtin_amdgcn_mfma_f32_16x16x32_bf16(a, wf[tap][1], acc[r2][s][1], 0, 0, 0);
                }
            }
        }

    #pragma unroll
    for (int r2 = 0; r2 < 2; ++r2) {
        const int y = y0 + 2 * wave + r2;
        if (y >= H_OUT) continue;
        #pragma unroll
        for (int s = 0; s < 4; ++s) {
            const int xo = x0 + s * 16 + 4 * g;
            #pragma unroll
            for (int h = 0; h < 2; ++h) {
                const int co = h * 16 + l15;
                float* op = out + (size_t)(n * C_OUT + co) * (H_OUT * W_OUT) + y * W_OUT + xo;
                const f32x4 v = acc[r2][s][h];
                if (xo + 3 < W_OUT) {
                    *reinterpret_cast<float2*>(op)     = make_float2(v[0], v[1]);
                    *reinterpret_cast<float2*>(op + 2) = make_float2(v[2], v[3]);
                } else {
                    #pragma unroll
                    for (int qq = 0; qq < 4; ++qq)
                        if (xo + qq < W_OUT) op[qq] = v[qq];
                }
            }
        }
    }
}

extern "C" void kernel_launch(void* const* d_in, const int* in_sizes, int n_in,
                              void* d_out, int out_size, void* d_ws, size_t ws_size,
                              hipStream_t stream) {
    const float* x = (const float*)d_in[0];
    const float* w = (const float*)d_in[1];
    float* out     = (float*)d_out;

    const size_t XT_BYTES = (size_t)N_B * H_IN * W_IN * C_IN * 2;   // 67108864
    const size_t WT_BYTES = 9 * C_OUT * C_IN * 2;                   // 18432

    if (ws_size >= XT_BYTES + WT_BYTES) {
        unsigned int*   xT = (unsigned int*)d_ws;
        unsigned short* wT = (unsigned short*)((char*)d_ws + XT_BYTES);
        hipLaunchKernelGGL(k1_tr,    dim3(N_B * H_IN), dim3(256), 0, stream, x, xT);
        hipLaunchKernelGGL(k0_packw, dim3(1),          dim3(256), 0, stream, w, wT);
        hipLaunchKernelGGL(k2_conv,  dim3(1024),       dim3(256), 0, stream,
                           (const unsigned short*)xT, wT, out);
    } else {
        hipLaunchKernelGGL(conv3x3_mfma, dim3(N_B * 128), dim3(256), 0, stream, x, w, out);
    }
}

// Round 4
// 112.335 us; speedup vs baseline: 3.4874x; 1.0512x over previous
//
#include <hip/hip_runtime.h>

#define N_B   16
#define C_IN  32
#define C_OUT 32
#define H_IN  256
#define W_IN  256
#define H_OUT 254
#define W_OUT 254

typedef __attribute__((ext_vector_type(8))) short bf16x8;
typedef __attribute__((ext_vector_type(4))) float f32x4;

__device__ __forceinline__ unsigned short f2bf(float f) {
    unsigned int u = __float_as_uint(f);
    unsigned int r = (u + 0x7FFFu + ((u >> 16) & 1u)) >> 16;   // RNE
    return (unsigned short)r;
}

// ---------------------------------------------------------------- K0: pack W
// w[co][ci][ky][kx] fp32  ->  wT[tap][co][ci] bf16 (18432 B)
__global__ void k0_packw(const float* __restrict__ w, unsigned short* __restrict__ wT) {
    for (int i = threadIdx.x; i < C_OUT * C_IN * 9; i += 256) {
        const int co  = i / 288;
        const int r   = i - co * 288;
        const int ci  = r / 9;
        const int tap = r - ci * 9;
        wT[(tap * C_OUT + co) * C_IN + ci] = f2bf(w[i]);
    }
}

// ---------------------------------------------------------- K1: NCHW -> NHWC
__global__ __launch_bounds__(256) void k1_tr(const float* __restrict__ x,
                                             unsigned int* __restrict__ xT) {
    __shared__ unsigned int row[4096];     // 16 KB = 256 col x 16 words(=32 ci)
    const int tid = threadIdx.x;
    const int b   = blockIdx.x;            // n*256 + y
    const float* src = x + (((size_t)(b >> 8)) << 21) + ((size_t)(b & 255) << 8);

    #pragma unroll
    for (int k = 0; k < 16; ++k) {
        const int id  = tid + (k << 8);
        const int col = id & 255;
        const int ci2 = id >> 8;           // pair of ci planes
        const float a = src[((size_t)ci2 << 17) + col];
        const float c = src[((size_t)ci2 << 17) + 65536 + col];
        row[(col << 4) | (ci2 ^ ((col >> 1) & 15))] =
            (unsigned)f2bf(a) | ((unsigned)f2bf(c) << 16);
    }
    __syncthreads();

    uint4* dst = (uint4*)(xT + ((size_t)b << 12));   // 16 KB per (n,y) row
    #pragma unroll
    for (int k = 0; k < 4; ++k) {
        const int id  = tid + (k << 8);    // 16B output chunk index
        const int col = id >> 2;
        const int c4  = id & 3;
        const int m   = (col >> 1) & 15;
        uint4 v;
        v.x = row[(col << 4) | (((c4 << 2) | 0) ^ m)];
        v.y = row[(col << 4) | (((c4 << 2) | 1) ^ m)];
        v.z = row[(col << 4) | (((c4 << 2) | 2) ^ m)];
        v.w = row[(col << 4) | (((c4 << 2) | 3) ^ m)];
        dst[id] = v;
    }
}

// ----------------------------------------------------------------- K2: conv
// One pass per wave: 2 output rows x 64 cols, all 32 co. No LDS, no barriers,
// no q-loop (no store->load vmcnt serialization). Explicit 1-row-position-
// ahead A-prefetch (Acur/Anxt, static indices) so every global load has a
// full MFMA step to complete. Weights fully hoisted (18 frags, L1-hot).
__global__ __launch_bounds__(256, 2)
void k2_conv(const unsigned short* __restrict__ xT,
             const unsigned short* __restrict__ wT,
             float* __restrict__ out) {
    const int tid  = threadIdx.x;
    const int bid  = blockIdx.x;
    // XCD-chunked swizzle (grid 2048 = 8 * 256, bijective)
    const int o    = ((bid & 7) << 8) | (bid >> 3);
    const int n    = o >> 7;               // image
    const int pb   = (o >> 2) & 31;        // 8-row block
    const int x0   = (o & 3) << 6;         // 64-col strip
    const int wave = tid >> 6;
    const int lane = tid & 63;
    const int l15  = lane & 15;
    const int g    = lane >> 4;

    const int R = (pb << 3) | (wave << 1); // output row pair base (even)
    if (R >= H_OUT) return;                // only pb=31/wave=3

    const char* rowbase = (const char*)xT
        + ((size_t)((n << 8) + R) << 14)          // input row R
        + ((x0 + l15) << 6) + (g << 4);
    const char* wbase = (const char*)wT + (l15 << 6) + (g << 4);

    // ---- all 18 weight B-frags
    bf16x8 wf[9][2];
    #pragma unroll
    for (int tap = 0; tap < 9; ++tap)
        #pragma unroll
        for (int h = 0; h < 2; ++h)
            wf[tap][h] = *(const bf16x8*)(wbase + (tap << 11) + (h << 10));

    f32x4 acc[2][4][2];
    #pragma unroll
    for (int r2 = 0; r2 < 2; ++r2)
        #pragma unroll
        for (int s = 0; s < 4; ++s)
            #pragma unroll
            for (int h = 0; h < 2; ++h) {
                f32x4 z = {0.f, 0.f, 0.f, 0.f};
                acc[r2][s][h] = z;
            }

    // ---- prologue: A-frags of input row R (P=0)
    bf16x8 Acur[12], Anxt[12];
    #pragma unroll
    for (int s = 0; s < 4; ++s)
        #pragma unroll
        for (int off = 0; off < 3; ++off)
            Acur[s * 3 + off] = *(const bf16x8*)(rowbase + (((s << 4) + off) << 6));

    // ---- 4 row-positions; A of row R+P feeds tap-row P (out row R) and
    //      tap-row P-1 (out row R+1)
    #pragma unroll
    for (int P = 0; P < 4; ++P) {
        if (P < 3) {
            const char* nrow = rowbase + ((size_t)(P + 1) << 14);
            #pragma unroll
            for (int s = 0; s < 4; ++s)
                #pragma unroll
                for (int off = 0; off < 3; ++off)
                    Anxt[s * 3 + off] = *(const bf16x8*)(nrow + (((s << 4) + off) << 6));
        }
        #pragma unroll
        for (int s = 0; s < 4; ++s)
            #pragma unroll
            for (int kx = 0; kx < 3; ++kx) {
                const bf16x8 a = Acur[s * 3 + kx];
                if (P <= 2) {
                    #pragma unroll
                    for (int h = 0; h < 2; ++h)
                        acc[0][s][h] = __builtin_amdgcn_mfma_f32_16x16x32_bf16(a, wf[P * 3 + kx][h], acc[0][s][h], 0, 0, 0);
                }
                if (P >= 1) {
                    #pragma unroll
                    for (int h = 0; h < 2; ++h)
                        acc[1][s][h] = __builtin_amdgcn_mfma_f32_16x16x32_bf16(a, wf[(P - 1) * 3 + kx][h], acc[1][s][h], 0, 0, 0);
                }
            }
        if (P < 3) {
            #pragma unroll
            for (int j = 0; j < 12; ++j) Acur[j] = Anxt[j];   // SSA-renamed
        }
    }

    // ---- store: D row = pixel 4g+q, col = co = h*16+l15
    #pragma unroll
    for (int r2 = 0; r2 < 2; ++r2) {
        const int y = R + r2;                   // < 254 (R even <= 252)
        #pragma unroll
        for (int h = 0; h < 2; ++h) {
            const int co = (h << 4) | l15;
            float* op = out + (size_t)((n << 5) + co) * (H_OUT * W_OUT)
                      + y * W_OUT + x0 + (g << 2);
            #pragma unroll
            for (int s = 0; s < 4; ++s) {
                const int xo = x0 + (s << 4) + (g << 2);
                const f32x4 v = acc[r2][s][h];
                float* p = op + (s << 4);
                if (xo + 3 < W_OUT) {
                    *(float2*)p       = make_float2(v[0], v[1]);
                    *(float2*)(p + 2) = make_float2(v[2], v[3]);
                } else if (xo + 1 < W_OUT) {    // xo==252 tail
                    *(float2*)p       = make_float2(v[0], v[1]);
                }
            }
        }
    }
}

// -------------------------------------------------- fallback (R1, verified)
#define ROWS_OUT 8
#define XT_OUT   64
#define IN_ROWS  10
#define IN_COLS  66

__global__ __launch_bounds__(256, 2)
void conv3x3_mfma(const float* __restrict__ x,
                  const float* __restrict__ w,
                  float* __restrict__ out) {
    __shared__ unsigned short w_lds[9 * C_OUT * C_IN];
    __shared__ unsigned short in_lds[IN_ROWS * IN_COLS * C_IN];

    const int tid  = threadIdx.x;
    const int b    = blockIdx.x;
    const int n    = b >> 7;
    const int rem  = b & 127;
    const int yt   = rem >> 2;
    const int xt   = rem & 3;
    const int y0   = yt * ROWS_OUT;
    const int x0   = xt * XT_OUT;
    const int wave = tid >> 6;
    const int lane = tid & 63;
    const int l15  = lane & 15;
    const int g    = lane >> 4;

    for (int i = tid; i < 9 * C_OUT * C_IN; i += 256) {
        const int co  = i / 288;
        const int r   = i - co * 288;
        const int ci  = r / 9;
        const int tap = r - ci * 9;
        w_lds[(tap * C_OUT + co) * C_IN + ci] = f2bf(w[i]);
    }
    __syncthreads();

    bf16x8 wf[9][2];
    #pragma unroll
    for (int tap = 0; tap < 9; ++tap)
        #pragma unroll
        for (int h = 0; h < 2; ++h)
            wf[tap][h] = *reinterpret_cast<const bf16x8*>(&w_lds[(tap * C_OUT + h * 16 + l15) * C_IN + g * 8]);

    const float* xn = x + ((size_t)n << 21);
    for (int it = tid; it < 4 * IN_ROWS * IN_COLS; it += 256) {
        const int col = it % IN_COLS;
        const int t2  = it / IN_COLS;
        const int row = t2 % IN_ROWS;
        const int ch  = t2 / IN_ROWS;
        const int iy  = y0 + row;
        const int ix  = x0 + col;
        const bool inb = (iy < H_IN) && (ix < W_IN);
        const float* src = xn + ((size_t)(ch * 8) << 16) + (iy << 8) + ix;
        bf16x8 pk;
        #pragma unroll
        for (int c = 0; c < 8; ++c)
            pk[c] = inb ? (short)f2bf(src[(size_t)c << 16]) : (short)0;
        const int p   = row * IN_COLS + col;
        const int swz = ch ^ ((p >> 1) & 3);
        *reinterpret_cast<bf16x8*>(&in_lds[p * C_IN + swz * 8]) = pk;
    }
    __syncthreads();

    f32x4 acc[2][4][2];
    #pragma unroll
    for (int r2 = 0; r2 < 2; ++r2)
        #pragma unroll
        for (int s = 0; s < 4; ++s)
            #pragma unroll
            for (int h = 0; h < 2; ++h) {
                f32x4 z = {0.f, 0.f, 0.f, 0.f};
                acc[r2][s][h] = z;
            }

    #pragma unroll
    for (int ky = 0; ky < 3; ++ky)
        #pragma unroll
        for (int kx = 0; kx < 3; ++kx) {
            const int tap = ky * 3 + kx;
            #pragma unroll
            for (int r2 = 0; r2 < 2; ++r2) {
                const int irow = 2 * wave + r2 + ky;
                #pragma unroll
                for (int s = 0; s < 4; ++s) {
                    const int p    = irow * IN_COLS + s * 16 + kx + l15;
                    const int swz  = g ^ ((p >> 1) & 3);
                    const bf16x8 a = *reinterpret_cast<const bf16x8*>(&in_lds[p * C_IN + swz * 8]);
                    acc[r2][s][0] = __builtin_amdgcn_mfma_f32_16x16x32_bf16(a, wf[tap][0], acc[r2][s][0], 0, 0, 0);
                    acc[r2][s][1] = __builtin_amdgcn_mfma_f32_16x16x32_bf16(a, wf[tap][1], acc[r2][s][1], 0, 0, 0);
                }
            }
        }

    #pragma unroll
    for (int r2 = 0; r2 < 2; ++r2) {
        const int y = y0 + 2 * wave + r2;
        if (y >= H_OUT) continue;
        #pragma unroll
        for (int s = 0; s < 4; ++s) {
            const int xo = x0 + s * 16 + 4 * g;
            #pragma unroll
            for (int h = 0; h < 2; ++h) {
                const int co = h * 16 + l15;
                float* op = out + (size_t)(n * C_OUT + co) * (H_OUT * W_OUT) + y * W_OUT + xo;
                const f32x4 v = acc[r2][s][h];
                if (xo + 3 < W_OUT) {
                    *reinterpret_cast<float2*>(op)     = make_float2(v[0], v[1]);
                    *reinterpret_cast<float2*>(op + 2) = make_float2(v[2], v[3]);
                } else {
                    #pragma unroll
                    for (int qq = 0; qq < 4; ++qq)
                        if (xo + qq < W_OUT) op[qq] = v[qq];
                }
            }
        }
    }
}

extern "C" void kernel_launch(void* const* d_in, const int* in_sizes, int n_in,
                              void* d_out, int out_size, void* d_ws, size_t ws_size,
                              hipStream_t stream) {
    const float* x = (const float*)d_in[0];
    const float* w = (const float*)d_in[1];
    float* out     = (float*)d_out;

    const size_t XT_BYTES = (size_t)N_B * H_IN * W_IN * C_IN * 2;   // 67108864
    const size_t WT_BYTES = 9 * C_OUT * C_IN * 2;                   // 18432

    if (ws_size >= XT_BYTES + WT_BYTES) {
        unsigned int*   xT = (unsigned int*)d_ws;
        unsigned short* wT = (unsigned short*)((char*)d_ws + XT_BYTES);
        hipLaunchKernelGGL(k1_tr,    dim3(N_B * H_IN), dim3(256), 0, stream, x, xT);
        hipLaunchKernelGGL(k0_packw, dim3(1),          dim3(256), 0, stream, w, wT);
        hipLaunchKernelGGL(k2_conv,  dim3(2048),       dim3(256), 0, stream,
                           (const unsigned short*)xT, wT, out);
    } else {
        hipLaunchKernelGGL(conv3x3_mfma, dim3(N_B * 128), dim3(256), 0, stream, x, w, out);
    }
}

// Round 5
// 100.327 us; speedup vs baseline: 3.9048x; 1.1197x over previous
//
#include <hip/hip_runtime.h>

#define N_B   16
#define C_IN  32
#define C_OUT 32
#define H_IN  256
#define W_IN  256
#define H_OUT 254
#define W_OUT 254

typedef __attribute__((ext_vector_type(8))) short bf16x8;
typedef __attribute__((ext_vector_type(4))) float f32x4;

__device__ __forceinline__ unsigned short f2bf(float f) {
    unsigned int u = __float_as_uint(f);
    unsigned int r = (u + 0x7FFFu + ((u >> 16) & 1u)) >> 16;   // RNE
    return (unsigned short)r;
}

#define GLOAD_LDS16(gaddr, laddr) \
    __builtin_amdgcn_global_load_lds((const __attribute__((address_space(1))) unsigned int*)(gaddr), \
                                     (__attribute__((address_space(3))) unsigned int*)(laddr), 16, 0, 0)

// ------------------------------------------------- K1: NCHW->NHWC (+weights)
// blocks 0..4095: x[n][ci][y][col] fp32 -> xT[n][y][col][ci] bf16
// block 4096:     w[co][ci][ky][kx] fp32 -> wT[tap][co][ci] bf16
__global__ __launch_bounds__(256) void k1_tr(const float* __restrict__ x,
                                             unsigned int* __restrict__ xT,
                                             const float* __restrict__ w,
                                             unsigned short* __restrict__ wT) {
    const int tid = threadIdx.x;
    const int b   = blockIdx.x;
    if (b == 4096) {                       // weight pack (one block)
        for (int i = tid; i < C_OUT * C_IN * 9; i += 256) {
            const int co  = i / 288;
            const int r   = i - co * 288;
            const int ci  = r / 9;
            const int tap = r - ci * 9;
            wT[(tap * C_OUT + co) * C_IN + ci] = f2bf(w[i]);
        }
        return;
    }
    __shared__ unsigned int row[4096];     // 16 KB = 256 col x 16 words(=32 ci)
    const float* src = x + (((size_t)(b >> 8)) << 21) + ((size_t)(b & 255) << 8);

    #pragma unroll
    for (int k = 0; k < 16; ++k) {
        const int id  = tid + (k << 8);
        const int col = id & 255;
        const int ci2 = id >> 8;           // pair of ci planes
        const float a = src[((size_t)ci2 << 17) + col];
        const float c = src[((size_t)ci2 << 17) + 65536 + col];
        row[(col << 4) | (ci2 ^ ((col >> 1) & 15))] =
            (unsigned)f2bf(a) | ((unsigned)f2bf(c) << 16);
    }
    __syncthreads();

    uint4* dst = (uint4*)(xT + ((size_t)b << 12));   // 16 KB per (n,y) row
    #pragma unroll
    for (int k = 0; k < 4; ++k) {
        const int id  = tid + (k << 8);    // 16B output chunk index
        const int col = id >> 2;
        const int c4  = id & 3;
        const int m   = (col >> 1) & 15;
        uint4 v;
        v.x = row[(col << 4) | (((c4 << 2) | 0) ^ m)];
        v.y = row[(col << 4) | (((c4 << 2) | 1) ^ m)];
        v.z = row[(col << 4) | (((c4 << 2) | 2) ^ m)];
        v.w = row[(col << 4) | (((c4 << 2) | 3) ^ m)];
        dst[id] = v;
    }
}

// ----------------------------------------------------------------- K2: conv
// Block: 8 out rows x 64 cols x 32 co. Input rows stream through a 4-slot LDS
// ring (5120 B/slot) staged via global_load_lds (zero VGPR staging, linear
// dest). Per step p: issue stage(p+3), each wave 12x ds_read_b128 A-frags
// (conflict-free contiguous 1KB pattern) + up to 48 MFMA, one barrier.
// ~3 blocks/CU overlap hides the per-step vmcnt drain.
#define ROWBUF_B 5120          // 80 px * 64 B (66 needed + pad to 5x1KB)
__global__ __launch_bounds__(256, 3)
void k2_conv(const unsigned short* __restrict__ xT,
             const unsigned short* __restrict__ wT,
             float* __restrict__ out) {
    __shared__ __align__(16) char ring[4][ROWBUF_B];   // 20 KB

    const int tid  = threadIdx.x;
    const int bid  = blockIdx.x;
    // XCD-chunked swizzle (grid 2048 = 8 * 256, bijective)
    const int o    = ((bid & 7) << 8) | (bid >> 3);
    const int n    = o >> 7;               // image
    const int pb   = (o >> 2) & 31;        // 8-row block
    const int x0   = (o & 3) << 6;         // 64-col strip
    const int wave = tid >> 6;
    const int lane = tid & 63;
    const int l15  = lane & 15;
    const int g    = lane >> 4;

    const int R0    = pb << 3;             // first out row of block
    const int orow  = R0 + (wave << 1);    // this wave's out-row pair
    const bool act0 = (orow     < H_OUT);
    const bool act1 = (orow + 1 < H_OUT);

    const size_t rowbase = ((size_t)((n << 8) + R0)) << 14;   // xT byte of row R0
    const int    goff    = (x0 << 6) + (wave << 10) + (lane << 4);

    // stage input row R0+r (80 px from col x0) into ring[slot]
    auto stage = [&](int r, int slot) {
        const char* gsrc = (const char*)xT + rowbase + (((size_t)r) << 14) + goff;
        char*       ldst = &ring[slot][0] + (wave << 10);      // wave-uniform
        GLOAD_LDS16(gsrc, ldst);
        if (wave == 0) GLOAD_LDS16(gsrc + 4096, ldst + 4096);  // tail KB
    };

    // ---- prologue: stage rows 0..2; load all 18 weight B-frags
    stage(0, 0); stage(1, 1); stage(2, 2);
    const char* wbase = (const char*)wT + (l15 << 6) + (g << 4);
    bf16x8 wf[9][2];
    #pragma unroll
    for (int tap = 0; tap < 9; ++tap)
        #pragma unroll
        for (int h = 0; h < 2; ++h)
            wf[tap][h] = *(const bf16x8*)(wbase + (tap << 11) + (h << 10));

    f32x4 acc[2][4][2];
    #pragma unroll
    for (int r2 = 0; r2 < 2; ++r2)
        #pragma unroll
        for (int s = 0; s < 4; ++s)
            #pragma unroll
            for (int h = 0; h < 2; ++h) {
                f32x4 z = {0.f, 0.f, 0.f, 0.f};
                acc[r2][s][h] = z;
            }

    __syncthreads();                       // rows 0..2 + weights resident

    const int pxoff = (l15 << 6) | (g << 4);

    // ---- stream 10 input rows
    #pragma unroll 1
    for (int p = 0; p < 10; ++p) {
        if (p <= 6) stage(p + 3, (p + 3) & 3);

        const int  ky0 = p - (wave << 1);        // tap row for r2=0
        const int  ky1 = ky0 - 1;                // tap row for r2=1
        const bool u0  = act0 && (ky0 >= 0) && (ky0 <= 2);
        const bool u1  = act1 && (ky1 >= 0) && (ky1 <= 2);

        if (u0 | u1) {
            const char* rb = &ring[p & 3][0] + pxoff;
            #pragma unroll
            for (int s = 0; s < 4; ++s) {
                const bf16x8 a0 = *(const bf16x8*)(rb + (s << 10));
                const bf16x8 a1 = *(const bf16x8*)(rb + (s << 10) + 64);
                const bf16x8 a2 = *(const bf16x8*)(rb + (s << 10) + 128);
                #pragma unroll
                for (int ky = 0; ky < 3; ++ky) {      // static wf/acc indices
                    if (u0 && ky0 == ky) {
                        #pragma unroll
                        for (int h = 0; h < 2; ++h) {
                            acc[0][s][h] = __builtin_amdgcn_mfma_f32_16x16x32_bf16(a0, wf[ky * 3 + 0][h], acc[0][s][h], 0, 0, 0);
                            acc[0][s][h] = __builtin_amdgcn_mfma_f32_16x16x32_bf16(a1, wf[ky * 3 + 1][h], acc[0][s][h], 0, 0, 0);
                            acc[0][s][h] = __builtin_amdgcn_mfma_f32_16x16x32_bf16(a2, wf[ky * 3 + 2][h], acc[0][s][h], 0, 0, 0);
                        }
                    }
                    if (u1 && ky1 == ky) {
                        #pragma unroll
                        for (int h = 0; h < 2; ++h) {
                            acc[1][s][h] = __builtin_amdgcn_mfma_f32_16x16x32_bf16(a0, wf[ky * 3 + 0][h], acc[1][s][h], 0, 0, 0);
                            acc[1][s][h] = __builtin_amdgcn_mfma_f32_16x16x32_bf16(a1, wf[ky * 3 + 1][h], acc[1][s][h], 0, 0, 0);
                            acc[1][s][h] = __builtin_amdgcn_mfma_f32_16x16x32_bf16(a2, wf[ky * 3 + 2][h], acc[1][s][h], 0, 0, 0);
                        }
                    }
                }
            }
        }
        __syncthreads();                   // arrival of staged row + WAW guard
    }

    // ---- store: D row = pixel 4g+q, col = co = h*16+l15
    #pragma unroll
    for (int r2 = 0; r2 < 2; ++r2) {
        if (!(r2 ? act1 : act0)) continue;
        const int y = orow + r2;
        #pragma unroll
        for (int h = 0; h < 2; ++h) {
            const int co = (h << 4) | l15;
            float* op = out + (size_t)((n << 5) + co) * (H_OUT * W_OUT)
                      + y * W_OUT + x0 + (g << 2);
            #pragma unroll
            for (int s = 0; s < 4; ++s) {
                const int xo = x0 + (s << 4) + (g << 2);
                const f32x4 v = acc[r2][s][h];
                float* p = op + (s << 4);
                if (xo + 3 < W_OUT) {
                    *(float2*)p       = make_float2(v[0], v[1]);
                    *(float2*)(p + 2) = make_float2(v[2], v[3]);
                } else if (xo + 1 < W_OUT) {    // xo==252 tail
                    *(float2*)p       = make_float2(v[0], v[1]);
                }
            }
        }
    }
}

// -------------------------------------------------- fallback (R1, verified)
#define ROWS_OUT 8
#define XT_OUT   64
#define IN_ROWS  10
#define IN_COLS  66

__global__ __launch_bounds__(256, 2)
void conv3x3_mfma(const float* __restrict__ x,
                  const float* __restrict__ w,
                  float* __restrict__ out) {
    __shared__ unsigned short w_lds[9 * C_OUT * C_IN];
    __shared__ unsigned short in_lds[IN_ROWS * IN_COLS * C_IN];

    const int tid  = threadIdx.x;
    const int b    = blockIdx.x;
    const int n    = b >> 7;
    const int rem  = b & 127;
    const int yt   = rem >> 2;
    const int xt   = rem & 3;
    const int y0   = yt * ROWS_OUT;
    const int x0   = xt * XT_OUT;
    const int wave = tid >> 6;
    const int lane = tid & 63;
    const int l15  = lane & 15;
    const int g    = lane >> 4;

    for (int i = tid; i < 9 * C_OUT * C_IN; i += 256) {
        const int co  = i / 288;
        const int r   = i - co * 288;
        const int ci  = r / 9;
        const int tap = r - ci * 9;
        w_lds[(tap * C_OUT + co) * C_IN + ci] = f2bf(w[i]);
    }
    __syncthreads();

    bf16x8 wf[9][2];
    #pragma unroll
    for (int tap = 0; tap < 9; ++tap)
        #pragma unroll
        for (int h = 0; h < 2; ++h)
            wf[tap][h] = *reinterpret_cast<const bf16x8*>(&w_lds[(tap * C_OUT + h * 16 + l15) * C_IN + g * 8]);

    const float* xn = x + ((size_t)n << 21);
    for (int it = tid; it < 4 * IN_ROWS * IN_COLS; it += 256) {
        const int col = it % IN_COLS;
        const int t2  = it / IN_COLS;
        const int row = t2 % IN_ROWS;
        const int ch  = t2 / IN_ROWS;
        const int iy  = y0 + row;
        const int ix  = x0 + col;
        const bool inb = (iy < H_IN) && (ix < W_IN);
        const float* src = xn + ((size_t)(ch * 8) << 16) + (iy << 8) + ix;
        bf16x8 pk;
        #pragma unroll
        for (int c = 0; c < 8; ++c)
            pk[c] = inb ? (short)f2bf(src[(size_t)c << 16]) : (short)0;
        const int p   = row * IN_COLS + col;
        const int swz = ch ^ ((p >> 1) & 3);
        *reinterpret_cast<bf16x8*>(&in_lds[p * C_IN + swz * 8]) = pk;
    }
    __syncthreads();

    f32x4 acc[2][4][2];
    #pragma unroll
    for (int r2 = 0; r2 < 2; ++r2)
        #pragma unroll
        for (int s = 0; s < 4; ++s)
            #pragma unroll
            for (int h = 0; h < 2; ++h) {
                f32x4 z = {0.f, 0.f, 0.f, 0.f};
                acc[r2][s][h] = z;
            }

    #pragma unroll
    for (int ky = 0; ky < 3; ++ky)
        #pragma unroll
        for (int kx = 0; kx < 3; ++kx) {
            const int tap = ky * 3 + kx;
            #pragma unroll
            for (int r2 = 0; r2 < 2; ++r2) {
                const int irow = 2 * wave + r2 + ky;
                #pragma unroll
                for (int s = 0; s < 4; ++s) {
                    const int p    = irow * IN_COLS + s * 16 + kx + l15;
                    const int swz  = g ^ ((p >> 1) & 3);
                    const bf16x8 a = *reinterpret_cast<const bf16x8*>(&in_lds[p * C_IN + swz * 8]);
                    acc[r2][s][0] = __builtin_amdgcn_mfma_f32_16x16x32_bf16(a, wf[tap][0], acc[r2][s][0], 0, 0, 0);
                    acc[r2][s][1] = __builtin_amdgcn_mfma_f32_16x16x32_bf16(a, wf[tap][1], acc[r2][s][1], 0, 0, 0);
                }
            }
        }

    #pragma unroll
    for (int r2 = 0; r2 < 2; ++r2) {
        const int y = y0 + 2 * wave + r2;
        if (y >= H_OUT) continue;
        #pragma unroll
        for (int s = 0; s < 4; ++s) {
            const int xo = x0 + s * 16 + 4 * g;
            #pragma unroll
            for (int h = 0; h < 2; ++h) {
                const int co = h * 16 + l15;
                float* op = out + (size_t)(n * C_OUT + co) * (H_OUT * W_OUT) + y * W_OUT + xo;
                const f32x4 v = acc[r2][s][h];
                if (xo + 3 < W_OUT) {
                    *reinterpret_cast<float2*>(op)     = make_float2(v[0], v[1]);
                    *reinterpret_cast<float2*>(op + 2) = make_float2(v[2], v[3]);
                } else {
                    #pragma unroll
                    for (int qq = 0; qq < 4; ++qq)
                        if (xo + qq < W_OUT) op[qq] = v[qq];
                }
            }
        }
    }
}

extern "C" void kernel_launch(void* const* d_in, const int* in_sizes, int n_in,
                              void* d_out, int out_size, void* d_ws, size_t ws_size,
                              hipStream_t stream) {
    const float* x = (const float*)d_in[0];
    const float* w = (const float*)d_in[1];
    float* out     = (float*)d_out;

    const size_t XT_BYTES = (size_t)N_B * H_IN * W_IN * C_IN * 2;   // 67108864
    const size_t WT_BYTES = 9 * C_OUT * C_IN * 2;                   // 18432
    const size_t SLACK    = 65536;          // k2 staging over-reach (reads only)

    if (ws_size >= XT_BYTES + WT_BYTES + SLACK) {
        unsigned int*   xT = (unsigned int*)d_ws;
        unsigned short* wT = (unsigned short*)((char*)d_ws + XT_BYTES);
        hipLaunchKernelGGL(k1_tr,   dim3(N_B * H_IN + 1), dim3(256), 0, stream, x, xT, w, wT);
        hipLaunchKernelGGL(k2_conv, dim3(2048),           dim3(256), 0, stream,
                           (const unsigned short*)xT, wT, out);
    } else {
        hipLaunchKernelGGL(conv3x3_mfma, dim3(N_B * 128), dim3(256), 0, stream, x, w, out);
    }
}

// Round 6
// 92.613 us; speedup vs baseline: 4.2300x; 1.0833x over previous
//
#include <hip/hip_runtime.h>

#define N_B   16
#define C_IN  32
#define C_OUT 32
#define H_IN  256
#define W_IN  256
#define H_OUT 254
#define W_OUT 254

typedef __attribute__((ext_vector_type(8))) short bf16x8;
typedef __attribute__((ext_vector_type(4))) float f32x4;

__device__ __forceinline__ unsigned short f2bf(float f) {
    unsigned int u = __float_as_uint(f);
    unsigned int r = (u + 0x7FFFu + ((u >> 16) & 1u)) >> 16;   // RNE
    return (unsigned short)r;
}

#define GLOAD_LDS16(gaddr, laddr) \
    __builtin_amdgcn_global_load_lds((const __attribute__((address_space(1))) unsigned int*)(gaddr), \
                                     (__attribute__((address_space(3))) unsigned int*)(laddr), 16, 0, 0)
#define GLOAD_LDS4(gaddr, laddr) \
    __builtin_amdgcn_global_load_lds((const __attribute__((address_space(1))) unsigned int*)(gaddr), \
                                     (__attribute__((address_space(3))) unsigned int*)(laddr), 4, 0, 0)

// ------------------------------------------------- K1: NCHW->NHWC (+weights)
__global__ __launch_bounds__(256) void k1_tr(const float* __restrict__ x,
                                             unsigned int* __restrict__ xT,
                                             const float* __restrict__ w,
                                             unsigned short* __restrict__ wT) {
    const int tid = threadIdx.x;
    const int b   = blockIdx.x;
    if (b == 4096) {                       // weight pack (one block)
        for (int i = tid; i < C_OUT * C_IN * 9; i += 256) {
            const int co  = i / 288;
            const int r   = i - co * 288;
            const int ci  = r / 9;
            const int tap = r - ci * 9;
            wT[(tap * C_OUT + co) * C_IN + ci] = f2bf(w[i]);
        }
        return;
    }
    __shared__ unsigned int row[4096];     // 16 KB = 256 col x 16 words(=32 ci)
    const float* src = x + (((size_t)(b >> 8)) << 21) + ((size_t)(b & 255) << 8);

    #pragma unroll
    for (int k = 0; k < 16; ++k) {
        const int id  = tid + (k << 8);
        const int col = id & 255;
        const int ci2 = id >> 8;           // pair of ci planes
        const float a = src[((size_t)ci2 << 17) + col];
        const float c = src[((size_t)ci2 << 17) + 65536 + col];
        row[(col << 4) | (ci2 ^ ((col >> 1) & 15))] =
            (unsigned)f2bf(a) | ((unsigned)f2bf(c) << 16);
    }
    __syncthreads();

    uint4* dst = (uint4*)(xT + ((size_t)b << 12));   // 16 KB per (n,y) row
    #pragma unroll
    for (int k = 0; k < 4; ++k) {
        const int id  = tid + (k << 8);    // 16B output chunk index
        const int col = id >> 2;
        const int c4  = id & 3;
        const int m   = (col >> 1) & 15;
        uint4 v;
        v.x = row[(col << 4) | (((c4 << 2) | 0) ^ m)];
        v.y = row[(col << 4) | (((c4 << 2) | 1) ^ m)];
        v.z = row[(col << 4) | (((c4 << 2) | 2) ^ m)];
        v.w = row[(col << 4) | (((c4 << 2) | 3) ^ m)];
        dst[id] = v;
    }
}

// ----------------------------------------------------------------- K2: conv
// BARRIER-FREE. Wave-private tile: 16 out cols x 8 out rows x 32 co.
// Each wave stages its own 20-px row chunks (1024B + 256B global_load_lds)
// into a private 4-slot LDS ring, 3 rows ahead; sync is counted
// s_waitcnt vmcnt(6) only (never 0 until tail) + sched_barrier fences.
// Weight frags issued FIRST so the vmcnt FIFO count drains W+stage0 at P=0.
// Completed row pairs store immediately (stores spread through the kernel).
#define MFMA_B16(a, b, c) __builtin_amdgcn_mfma_f32_16x16x32_bf16((a), (b), (c), 0, 0, 0)

#define K2_STAGE(R_, S_) do {                                              \
    const char* gs_ = gx + ((size_t)(R_) << 14);                           \
    char* ld_ = myring + (S_) * 1280;                                      \
    GLOAD_LDS16(gs_ + (lane << 4), ld_);                                   \
    GLOAD_LDS4(gs_ + 1024 + (lane << 2), ld_ + 1024);                      \
} while (0)

#define K2_PAIR(P_, Q_) do {                                               \
    if ((P_) - 2 * (Q_) >= 0 && (P_) - 2 * (Q_) <= 2) {                    \
        const int ky_ = (P_) - 2 * (Q_);                                   \
        acc[Q_][0][0] = MFMA_B16(a0, wf[ky_ * 3 + 0][0], acc[Q_][0][0]);   \
        acc[Q_][0][0] = MFMA_B16(a1, wf[ky_ * 3 + 1][0], acc[Q_][0][0]);   \
        acc[Q_][0][0] = MFMA_B16(a2, wf[ky_ * 3 + 2][0], acc[Q_][0][0]);   \
        acc[Q_][0][1] = MFMA_B16(a0, wf[ky_ * 3 + 0][1], acc[Q_][0][1]);   \
        acc[Q_][0][1] = MFMA_B16(a1, wf[ky_ * 3 + 1][1], acc[Q_][0][1]);   \
        acc[Q_][0][1] = MFMA_B16(a2, wf[ky_ * 3 + 2][1], acc[Q_][0][1]);   \
    }                                                                      \
    if ((P_) - 2 * (Q_) - 1 >= 0 && (P_) - 2 * (Q_) - 1 <= 2) {            \
        const int ky_ = (P_) - 2 * (Q_) - 1;                               \
        acc[Q_][1][0] = MFMA_B16(a0, wf[ky_ * 3 + 0][0], acc[Q_][1][0]);   \
        acc[Q_][1][0] = MFMA_B16(a1, wf[ky_ * 3 + 1][0], acc[Q_][1][0]);   \
        acc[Q_][1][0] = MFMA_B16(a2, wf[ky_ * 3 + 2][0], acc[Q_][1][0]);   \
        acc[Q_][1][1] = MFMA_B16(a0, wf[ky_ * 3 + 0][1], acc[Q_][1][1]);   \
        acc[Q_][1][1] = MFMA_B16(a1, wf[ky_ * 3 + 1][1], acc[Q_][1][1]);   \
        acc[Q_][1][1] = MFMA_B16(a2, wf[ky_ * 3 + 2][1], acc[Q_][1][1]);   \
    }                                                                      \
} while (0)

#define K2_STEP(P_, VM_, DOSTAGE_) do {                                    \
    __builtin_amdgcn_sched_barrier(0);                                     \
    if (DOSTAGE_) { K2_STAGE((P_) + 3, ((P_) + 3) & 3); }                  \
    __builtin_amdgcn_sched_barrier(0);                                     \
    asm volatile("s_waitcnt vmcnt(" #VM_ ")" ::: "memory");                \
    __builtin_amdgcn_sched_barrier(0);                                     \
    const char* rb_ = myring + ((P_) & 3) * 1280 + (l15 << 6) + (g << 4);  \
    const bf16x8 a0 = *(const bf16x8*)(rb_);                               \
    const bf16x8 a1 = *(const bf16x8*)(rb_ + 64);                          \
    const bf16x8 a2 = *(const bf16x8*)(rb_ + 128);                         \
    K2_PAIR(P_, 0); K2_PAIR(P_, 1); K2_PAIR(P_, 2); K2_PAIR(P_, 3);        \
} while (0)

#define K2_STORE_HALF(Q_, R2_) do {                                        \
    const int y_ = R0 + 2 * (Q_) + (R2_);                                  \
    if (y_ < H_OUT) {                                                      \
        const int xo_ = xw + (g << 2);                                     \
        float* op0_ = out + (size_t)((n << 5) | l15) * (H_OUT * W_OUT)     \
                    + y_ * W_OUT + xo_;                                    \
        float* op1_ = out + (size_t)((n << 5) | 16 | l15) * (H_OUT * W_OUT)\
                    + y_ * W_OUT + xo_;                                    \
        const f32x4 v0_ = acc[Q_][R2_][0];                                 \
        const f32x4 v1_ = acc[Q_][R2_][1];                                 \
        if (xo_ + 3 < W_OUT) {                                             \
            *(float2*)op0_       = make_float2(v0_[0], v0_[1]);            \
            *(float2*)(op0_ + 2) = make_float2(v0_[2], v0_[3]);            \
            *(float2*)op1_       = make_float2(v1_[0], v1_[1]);            \
            *(float2*)(op1_ + 2) = make_float2(v1_[2], v1_[3]);            \
        } else if (xo_ + 1 < W_OUT) {                                      \
            *(float2*)op0_ = make_float2(v0_[0], v0_[1]);                  \
            *(float2*)op1_ = make_float2(v1_[0], v1_[1]);                  \
        }                                                                  \
    }                                                                      \
} while (0)

__global__ __launch_bounds__(256, 2)
void k2_conv(const unsigned short* __restrict__ xT,
             const unsigned short* __restrict__ wT,
             float* __restrict__ out) {
    __shared__ __align__(16) char ring[4][4][1280];   // [wave][slot] 20 KB

    const int tid  = threadIdx.x;
    const int bid  = blockIdx.x;
    const int o    = ((bid & 7) << 8) | (bid >> 3);   // XCD-chunked, bijective
    const int n    = o >> 7;
    const int pb   = (o >> 2) & 31;
    const int x0   = (o & 3) << 6;
    const int wave = tid >> 6;
    const int lane = tid & 63;
    const int l15  = lane & 15;
    const int g    = lane >> 4;
    const int xw   = x0 + (wave << 4);     // wave's 16-col sub-strip
    const int R0   = pb << 3;

    const size_t rowbase = ((size_t)((n << 8) + R0)) << 14;
    const char*  gx      = (const char*)xT + rowbase + (xw << 6);
    char*        myring  = &ring[wave][0][0];

    // ---- weight frags FIRST (oldest in vmcnt FIFO)
    const char* wbase = (const char*)wT + (l15 << 6) + (g << 4);
    bf16x8 wf[9][2];
    #pragma unroll
    for (int tap = 0; tap < 9; ++tap)
        #pragma unroll
        for (int h = 0; h < 2; ++h)
            wf[tap][h] = *(const bf16x8*)(wbase + (tap << 11) + (h << 10));
    __builtin_amdgcn_sched_barrier(0);

    // ---- prologue: stage rows 0..2 (6 loads in flight)
    K2_STAGE(0, 0);
    K2_STAGE(1, 1);
    K2_STAGE(2, 2);
    __builtin_amdgcn_sched_barrier(0);

    f32x4 acc[4][2][2];
    #pragma unroll
    for (int q = 0; q < 4; ++q)
        #pragma unroll
        for (int r2 = 0; r2 < 2; ++r2)
            #pragma unroll
            for (int h = 0; h < 2; ++h) {
                f32x4 z = {0.f, 0.f, 0.f, 0.f};
                acc[q][r2][h] = z;
            }

    // ---- 10 steps, fully unrolled; steady-state vmcnt(6), tail 4/2/0
    K2_STEP(0, 6, 1);
    K2_STEP(1, 6, 1);
    K2_STEP(2, 6, 1);
    K2_STEP(3, 6, 1);  K2_STORE_HALF(0, 0); K2_STORE_HALF(0, 1);
    K2_STEP(4, 6, 1);
    K2_STEP(5, 6, 1);  K2_STORE_HALF(1, 0); K2_STORE_HALF(1, 1);
    K2_STEP(6, 6, 1);
    K2_STEP(7, 4, 0);  K2_STORE_HALF(2, 0); K2_STORE_HALF(2, 1);
    K2_STEP(8, 2, 0);
    K2_STEP(9, 0, 0);  K2_STORE_HALF(3, 0); K2_STORE_HALF(3, 1);
}

// -------------------------------------------------- fallback (R1, verified)
#define ROWS_OUT 8
#define XT_OUT   64
#define IN_ROWS  10
#define IN_COLS  66

__global__ __launch_bounds__(256, 2)
void conv3x3_mfma(const float* __restrict__ x,
                  const float* __restrict__ w,
                  float* __restrict__ out) {
    __shared__ unsigned short w_lds[9 * C_OUT * C_IN];
    __shared__ unsigned short in_lds[IN_ROWS * IN_COLS * C_IN];

    const int tid  = threadIdx.x;
    const int b    = blockIdx.x;
    const int n    = b >> 7;
    const int rem  = b & 127;
    const int yt   = rem >> 2;
    const int xt   = rem & 3;
    const int y0   = yt * ROWS_OUT;
    const int x0   = xt * XT_OUT;
    const int wave = tid >> 6;
    const int lane = tid & 63;
    const int l15  = lane & 15;
    const int g    = lane >> 4;

    for (int i = tid; i < 9 * C_OUT * C_IN; i += 256) {
        const int co  = i / 288;
        const int r   = i - co * 288;
        const int ci  = r / 9;
        const int tap = r - ci * 9;
        w_lds[(tap * C_OUT + co) * C_IN + ci] = f2bf(w[i]);
    }
    __syncthreads();

    bf16x8 wf[9][2];
    #pragma unroll
    for (int tap = 0; tap < 9; ++tap)
        #pragma unroll
        for (int h = 0; h < 2; ++h)
            wf[tap][h] = *reinterpret_cast<const bf16x8*>(&w_lds[(tap * C_OUT + h * 16 + l15) * C_IN + g * 8]);

    const float* xn = x + ((size_t)n << 21);
    for (int it = tid; it < 4 * IN_ROWS * IN_COLS; it += 256) {
        const int col = it % IN_COLS;
        const int t2  = it / IN_COLS;
        const int row = t2 % IN_ROWS;
        const int ch  = t2 / IN_ROWS;
        const int iy  = y0 + row;
        const int ix  = x0 + col;
        const bool inb = (iy < H_IN) && (ix < W_IN);
        const float* src = xn + ((size_t)(ch * 8) << 16) + (iy << 8) + ix;
        bf16x8 pk;
        #pragma unroll
        for (int c = 0; c < 8; ++c)
            pk[c] = inb ? (short)f2bf(src[(size_t)c << 16]) : (short)0;
        const int p   = row * IN_COLS + col;
        const int swz = ch ^ ((p >> 1) & 3);
        *reinterpret_cast<bf16x8*>(&in_lds[p * C_IN + swz * 8]) = pk;
    }
    __syncthreads();

    f32x4 acc[2][4][2];
    #pragma unroll
    for (int r2 = 0; r2 < 2; ++r2)
        #pragma unroll
        for (int s = 0; s < 4; ++s)
            #pragma unroll
            for (int h = 0; h < 2; ++h) {
                f32x4 z = {0.f, 0.f, 0.f, 0.f};
                acc[r2][s][h] = z;
            }

    #pragma unroll
    for (int ky = 0; ky < 3; ++ky)
        #pragma unroll
        for (int kx = 0; kx < 3; ++kx) {
            const int tap = ky * 3 + kx;
            #pragma unroll
            for (int r2 = 0; r2 < 2; ++r2) {
                const int irow = 2 * wave + r2 + ky;
                #pragma unroll
                for (int s = 0; s < 4; ++s) {
                    const int p    = irow * IN_COLS + s * 16 + kx + l15;
                    const int swz  = g ^ ((p >> 1) & 3);
                    const bf16x8 a = *reinterpret_cast<const bf16x8*>(&in_lds[p * C_IN + swz * 8]);
                    acc[r2][s][0] = __builtin_amdgcn_mfma_f32_16x16x32_bf16(a, wf[tap][0], acc[r2][s][0], 0, 0, 0);
                    acc[r2][s][1] = __builtin_amdgcn_mfma_f32_16x16x32_bf16(a, wf[tap][1], acc[r2][s][1], 0, 0, 0);
                }
            }
        }

    #pragma unroll
    for (int r2 = 0; r2 < 2; ++r2) {
        const int y = y0 + 2 * wave + r2;
        if (y >= H_OUT) continue;
        #pragma unroll
        for (int s = 0; s < 4; ++s) {
            const int xo = x0 + s * 16 + 4 * g;
            #pragma unroll
            for (int h = 0; h < 2; ++h) {
                const int co = h * 16 + l15;
                float* op = out + (size_t)(n * C_OUT + co) * (H_OUT * W_OUT) + y * W_OUT + xo;
                const f32x4 v = acc[r2][s][h];
                if (xo + 3 < W_OUT) {
                    *reinterpret_cast<float2*>(op)     = make_float2(v[0], v[1]);
                    *reinterpret_cast<float2*>(op + 2) = make_float2(v[2], v[3]);
                } else {
                    #pragma unroll
                    for (int qq = 0; qq < 4; ++qq)
                        if (xo + qq < W_OUT) op[qq] = v[qq];
                }
            }
        }
    }
}

extern "C" void kernel_launch(void* const* d_in, const int* in_sizes, int n_in,
                              void* d_out, int out_size, void* d_ws, size_t ws_size,
                              hipStream_t stream) {
    const float* x = (const float*)d_in[0];
    const float* w = (const float*)d_in[1];
    float* out     = (float*)d_out;

    const size_t XT_BYTES = (size_t)N_B * H_IN * W_IN * C_IN * 2;   // 67108864
    const size_t WT_BYTES = 9 * C_OUT * C_IN * 2;                   // 18432
    const size_t SLACK    = 131072;         // k2 staging over-reach (reads only)

    if (ws_size >= XT_BYTES + WT_BYTES + SLACK) {
        unsigned int*   xT = (unsigned int*)d_ws;
        unsigned short* wT = (unsigned short*)((char*)d_ws + XT_BYTES);
        hipLaunchKernelGGL(k1_tr,   dim3(N_B * H_IN + 1), dim3(256), 0, stream, x, xT, w, wT);
        hipLaunchKernelGGL(k2_conv, dim3(2048),           dim3(256), 0, stream,
                           (const unsigned short*)xT, wT, out);
    } else {
        hipLaunchKernelGGL(conv3x3_mfma, dim3(N_B * 128), dim3(256), 0, stream, x, w, out);
    }
}

// Round 7
// 90.651 us; speedup vs baseline: 4.3216x; 1.0216x over previous
//
#include <hip/hip_runtime.h>

#define N_B   16
#define C_IN  32
#define C_OUT 32
#define H_IN  256
#define W_IN  256
#define H_OUT 254
#define W_OUT 254

typedef __attribute__((ext_vector_type(8))) short bf16x8;
typedef __attribute__((ext_vector_type(4))) float f32x4;

__device__ __forceinline__ unsigned short f2bf(float f) {
    unsigned int u = __float_as_uint(f);
    unsigned int r = (u + 0x7FFFu + ((u >> 16) & 1u)) >> 16;   // RNE
    return (unsigned short)r;
}

#define GLOAD_LDS16(gaddr, laddr) \
    __builtin_amdgcn_global_load_lds((const __attribute__((address_space(1))) unsigned int*)(gaddr), \
                                     (__attribute__((address_space(3))) unsigned int*)(laddr), 16, 0, 0)
#define GLOAD_LDS4(gaddr, laddr) \
    __builtin_amdgcn_global_load_lds((const __attribute__((address_space(1))) unsigned int*)(gaddr), \
                                     (__attribute__((address_space(3))) unsigned int*)(laddr), 4, 0, 0)

// ------------------------------------------------- K1: NCHW->NHWC (+weights)
__global__ __launch_bounds__(256) void k1_tr(const float* __restrict__ x,
                                             unsigned int* __restrict__ xT,
                                             const float* __restrict__ w,
                                             unsigned short* __restrict__ wT) {
    const int tid = threadIdx.x;
    const int b   = blockIdx.x;
    if (b == 4096) {                       // weight pack (one block)
        for (int i = tid; i < C_OUT * C_IN * 9; i += 256) {
            const int co  = i / 288;
            const int r   = i - co * 288;
            const int ci  = r / 9;
            const int tap = r - ci * 9;
            wT[(tap * C_OUT + co) * C_IN + ci] = f2bf(w[i]);
        }
        return;
    }
    __shared__ unsigned int row[4096];     // 16 KB = 256 col x 16 words(=32 ci)
    const float* src = x + (((size_t)(b >> 8)) << 21) + ((size_t)(b & 255) << 8);

    #pragma unroll
    for (int k = 0; k < 16; ++k) {
        const int id  = tid + (k << 8);
        const int col = id & 255;
        const int ci2 = id >> 8;           // pair of ci planes
        const float a = src[((size_t)ci2 << 17) + col];
        const float c = src[((size_t)ci2 << 17) + 65536 + col];
        row[(col << 4) | (ci2 ^ ((col >> 1) & 15))] =
            (unsigned)f2bf(a) | ((unsigned)f2bf(c) << 16);
    }
    __syncthreads();

    uint4* dst = (uint4*)(xT + ((size_t)b << 12));   // 16 KB per (n,y) row
    #pragma unroll
    for (int k = 0; k < 4; ++k) {
        const int id  = tid + (k << 8);    // 16B output chunk index
        const int col = id >> 2;
        const int c4  = id & 3;
        const int m   = (col >> 1) & 15;
        uint4 v;
        v.x = row[(col << 4) | (((c4 << 2) | 0) ^ m)];
        v.y = row[(col << 4) | (((c4 << 2) | 1) ^ m)];
        v.z = row[(col << 4) | (((c4 << 2) | 2) ^ m)];
        v.w = row[(col << 4) | (((c4 << 2) | 3) ^ m)];
        dst[id] = v;
    }
}

// ----------------------------------------------------------------- K2: conv
// BARRIER-FREE, 5-deep. Wave-private tile: 16 out cols x 8 out rows x 32 co.
// Each wave stages its own 20-px row chunks into a private 8-slot LDS ring,
// FIVE rows ahead; sync is counted s_waitcnt vmcnt(10) (never 0 until tail)
// + sched_barrier fences. ~1300 cyc in-wave cover + 3 waves/SIMD TLP.
#define MFMA_B16(a, b, c) __builtin_amdgcn_mfma_f32_16x16x32_bf16((a), (b), (c), 0, 0, 0)

#define K2_STAGE(R_) do {                                                  \
    const char* gs_ = gx + ((size_t)(R_) << 14);                           \
    char* ld_ = myring + ((R_) & 7) * 1280;                                \
    GLOAD_LDS16(gs_ + (lane << 4), ld_);                                   \
    GLOAD_LDS4(gs_ + 1024 + (lane << 2), ld_ + 1024);                      \
} while (0)

#define K2_PAIR(P_, Q_) do {                                               \
    if ((P_) - 2 * (Q_) >= 0 && (P_) - 2 * (Q_) <= 2) {                    \
        const int ky_ = (P_) - 2 * (Q_);                                   \
        acc[Q_][0][0] = MFMA_B16(a0, wf[ky_ * 3 + 0][0], acc[Q_][0][0]);   \
        acc[Q_][0][0] = MFMA_B16(a1, wf[ky_ * 3 + 1][0], acc[Q_][0][0]);   \
        acc[Q_][0][0] = MFMA_B16(a2, wf[ky_ * 3 + 2][0], acc[Q_][0][0]);   \
        acc[Q_][0][1] = MFMA_B16(a0, wf[ky_ * 3 + 0][1], acc[Q_][0][1]);   \
        acc[Q_][0][1] = MFMA_B16(a1, wf[ky_ * 3 + 1][1], acc[Q_][0][1]);   \
        acc[Q_][0][1] = MFMA_B16(a2, wf[ky_ * 3 + 2][1], acc[Q_][0][1]);   \
    }                                                                      \
    if ((P_) - 2 * (Q_) - 1 >= 0 && (P_) - 2 * (Q_) - 1 <= 2) {            \
        const int ky_ = (P_) - 2 * (Q_) - 1;                               \
        acc[Q_][1][0] = MFMA_B16(a0, wf[ky_ * 3 + 0][0], acc[Q_][1][0]);   \
        acc[Q_][1][0] = MFMA_B16(a1, wf[ky_ * 3 + 1][0], acc[Q_][1][0]);   \
        acc[Q_][1][0] = MFMA_B16(a2, wf[ky_ * 3 + 2][0], acc[Q_][1][0]);   \
        acc[Q_][1][1] = MFMA_B16(a0, wf[ky_ * 3 + 0][1], acc[Q_][1][1]);   \
        acc[Q_][1][1] = MFMA_B16(a1, wf[ky_ * 3 + 1][1], acc[Q_][1][1]);   \
        acc[Q_][1][1] = MFMA_B16(a2, wf[ky_ * 3 + 2][1], acc[Q_][1][1]);   \
    }                                                                      \
} while (0)

#define K2_STEP(P_, VM_, DOSTAGE_) do {                                    \
    __builtin_amdgcn_sched_barrier(0);                                     \
    if (DOSTAGE_) { K2_STAGE((P_) + 5); }                                  \
    __builtin_amdgcn_sched_barrier(0);                                     \
    asm volatile("s_waitcnt vmcnt(" #VM_ ")" ::: "memory");                \
    __builtin_amdgcn_sched_barrier(0);                                     \
    const char* rb_ = myring + ((P_) & 7) * 1280 + (l15 << 6) + (g << 4);  \
    const bf16x8 a0 = *(const bf16x8*)(rb_);                               \
    const bf16x8 a1 = *(const bf16x8*)(rb_ + 64);                          \
    const bf16x8 a2 = *(const bf16x8*)(rb_ + 128);                         \
    K2_PAIR(P_, 0); K2_PAIR(P_, 1); K2_PAIR(P_, 2); K2_PAIR(P_, 3);        \
} while (0)

#define K2_STORE_HALF(Q_, R2_) do {                                        \
    const int y_ = R0 + 2 * (Q_) + (R2_);                                  \
    if (y_ < H_OUT) {                                                      \
        const int xo_ = xw + (g << 2);                                     \
        float* op0_ = out + (size_t)((n << 5) | l15) * (H_OUT * W_OUT)     \
                    + y_ * W_OUT + xo_;                                    \
        float* op1_ = out + (size_t)((n << 5) | 16 | l15) * (H_OUT * W_OUT)\
                    + y_ * W_OUT + xo_;                                    \
        const f32x4 v0_ = acc[Q_][R2_][0];                                 \
        const f32x4 v1_ = acc[Q_][R2_][1];                                 \
        if (xo_ + 3 < W_OUT) {                                             \
            *(float2*)op0_       = make_float2(v0_[0], v0_[1]);            \
            *(float2*)(op0_ + 2) = make_float2(v0_[2], v0_[3]);            \
            *(float2*)op1_       = make_float2(v1_[0], v1_[1]);            \
            *(float2*)(op1_ + 2) = make_float2(v1_[2], v1_[3]);            \
        } else if (xo_ + 1 < W_OUT) {                                      \
            *(float2*)op0_ = make_float2(v0_[0], v0_[1]);                  \
            *(float2*)op1_ = make_float2(v1_[0], v1_[1]);                  \
        }                                                                  \
    }                                                                      \
} while (0)

__global__ __launch_bounds__(256, 3)
void k2_conv(const unsigned short* __restrict__ xT,
             const unsigned short* __restrict__ wT,
             float* __restrict__ out) {
    __shared__ __align__(16) char ring[4][8][1280];   // [wave][slot] 40 KB

    const int tid  = threadIdx.x;
    const int bid  = blockIdx.x;
    const int o    = ((bid & 7) << 8) | (bid >> 3);   // XCD-chunked, bijective
    const int n    = o >> 7;
    const int pb   = (o >> 2) & 31;
    const int x0   = (o & 3) << 6;
    const int wave = tid >> 6;
    const int lane = tid & 63;
    const int l15  = lane & 15;
    const int g    = lane >> 4;
    const int xw   = x0 + (wave << 4);     // wave's 16-col sub-strip
    const int R0   = pb << 3;

    const size_t rowbase = ((size_t)((n << 8) + R0)) << 14;
    const char*  gx      = (const char*)xT + rowbase + (xw << 6);
    char*        myring  = &ring[wave][0][0];

    // ---- weight frags FIRST (oldest in vmcnt FIFO)
    const char* wbase = (const char*)wT + (l15 << 6) + (g << 4);
    bf16x8 wf[9][2];
    #pragma unroll
    for (int tap = 0; tap < 9; ++tap)
        #pragma unroll
        for (int h = 0; h < 2; ++h)
            wf[tap][h] = *(const bf16x8*)(wbase + (tap << 11) + (h << 10));
    __builtin_amdgcn_sched_barrier(0);

    // ---- prologue: stage rows 0..4 (10 loads in flight)
    K2_STAGE(0);
    K2_STAGE(1);
    K2_STAGE(2);
    K2_STAGE(3);
    K2_STAGE(4);
    __builtin_amdgcn_sched_barrier(0);

    f32x4 acc[4][2][2];
    #pragma unroll
    for (int q = 0; q < 4; ++q)
        #pragma unroll
        for (int r2 = 0; r2 < 2; ++r2)
            #pragma unroll
            for (int h = 0; h < 2; ++h) {
                f32x4 z = {0.f, 0.f, 0.f, 0.f};
                acc[q][r2][h] = z;
            }

    // ---- 10 steps, fully unrolled; steady-state vmcnt(10), tail 8/6/4/2/0
    K2_STEP(0, 10, 1);
    K2_STEP(1, 10, 1);
    K2_STEP(2, 10, 1);
    K2_STEP(3, 10, 1);  K2_STORE_HALF(0, 0); K2_STORE_HALF(0, 1);
    K2_STEP(4, 10, 1);
    K2_STEP(5, 8, 0);   K2_STORE_HALF(1, 0); K2_STORE_HALF(1, 1);
    K2_STEP(6, 6, 0);
    K2_STEP(7, 4, 0);   K2_STORE_HALF(2, 0); K2_STORE_HALF(2, 1);
    K2_STEP(8, 2, 0);
    K2_STEP(9, 0, 0);   K2_STORE_HALF(3, 0); K2_STORE_HALF(3, 1);
}

// -------------------------------------------------- fallback (R1, verified)
#define ROWS_OUT 8
#define XT_OUT   64
#define IN_ROWS  10
#define IN_COLS  66

__global__ __launch_bounds__(256, 2)
void conv3x3_mfma(const float* __restrict__ x,
                  const float* __restrict__ w,
                  float* __restrict__ out) {
    __shared__ unsigned short w_lds[9 * C_OUT * C_IN];
    __shared__ unsigned short in_lds[IN_ROWS * IN_COLS * C_IN];

    const int tid  = threadIdx.x;
    const int b    = blockIdx.x;
    const int n    = b >> 7;
    const int rem  = b & 127;
    const int yt   = rem >> 2;
    const int xt   = rem & 3;
    const int y0   = yt * ROWS_OUT;
    const int x0   = xt * XT_OUT;
    const int wave = tid >> 6;
    const int lane = tid & 63;
    const int l15  = lane & 15;
    const int g    = lane >> 4;

    for (int i = tid; i < 9 * C_OUT * C_IN; i += 256) {
        const int co  = i / 288;
        const int r   = i - co * 288;
        const int ci  = r / 9;
        const int tap = r - ci * 9;
        w_lds[(tap * C_OUT + co) * C_IN + ci] = f2bf(w[i]);
    }
    __syncthreads();

    bf16x8 wf[9][2];
    #pragma unroll
    for (int tap = 0; tap < 9; ++tap)
        #pragma unroll
        for (int h = 0; h < 2; ++h)
            wf[tap][h] = *reinterpret_cast<const bf16x8*>(&w_lds[(tap * C_OUT + h * 16 + l15) * C_IN + g * 8]);

    const float* xn = x + ((size_t)n << 21);
    for (int it = tid; it < 4 * IN_ROWS * IN_COLS; it += 256) {
        const int col = it % IN_COLS;
        const int t2  = it / IN_COLS;
        const int row = t2 % IN_ROWS;
        const int ch  = t2 / IN_ROWS;
        const int iy  = y0 + row;
        const int ix  = x0 + col;
        const bool inb = (iy < H_IN) && (ix < W_IN);
        const float* src = xn + ((size_t)(ch * 8) << 16) + (iy << 8) + ix;
        bf16x8 pk;
        #pragma unroll
        for (int c = 0; c < 8; ++c)
            pk[c] = inb ? (short)f2bf(src[(size_t)c << 16]) : (short)0;
        const int p   = row * IN_COLS + col;
        const int swz = ch ^ ((p >> 1) & 3);
        *reinterpret_cast<bf16x8*>(&in_lds[p * C_IN + swz * 8]) = pk;
    }
    __syncthreads();

    f32x4 acc[2][4][2];
    #pragma unroll
    for (int r2 = 0; r2 < 2; ++r2)
        #pragma unroll
        for (int s = 0; s < 4; ++s)
            #pragma unroll
            for (int h = 0; h < 2; ++h) {
                f32x4 z = {0.f, 0.f, 0.f, 0.f};
                acc[r2][s][h] = z;
            }

    #pragma unroll
    for (int ky = 0; ky < 3; ++ky)
        #pragma unroll
        for (int kx = 0; kx < 3; ++kx) {
            const int tap = ky * 3 + kx;
            #pragma unroll
            for (int r2 = 0; r2 < 2; ++r2) {
                const int irow = 2 * wave + r2 + ky;
                #pragma unroll
                for (int s = 0; s < 4; ++s) {
                    const int p    = irow * IN_COLS + s * 16 + kx + l15;
                    const int swz  = g ^ ((p >> 1) & 3);
                    const bf16x8 a = *reinterpret_cast<const bf16x8*>(&in_lds[p * C_IN + swz * 8]);
                    acc[r2][s][0] = __builtin_amdgcn_mfma_f32_16x16x32_bf16(a, wf[tap][0], acc[r2][s][0], 0, 0, 0);
                    acc[r2][s][1] = __builtin_amdgcn_mfma_f32_16x16x32_bf16(a, wf[tap][1], acc[r2][s][1], 0, 0, 0);
                }
            }
        }

    #pragma unroll
    for (int r2 = 0; r2 < 2; ++r2) {
        const int y = y0 + 2 * wave + r2;
        if (y >= H_OUT) continue;
        #pragma unroll
        for (int s = 0; s < 4; ++s) {
            const int xo = x0 + s * 16 + 4 * g;
            #pragma unroll
            for (int h = 0; h < 2; ++h) {
                const int co = h * 16 + l15;
                float* op = out + (size_t)(n * C_OUT + co) * (H_OUT * W_OUT) + y * W_OUT + xo;
                const f32x4 v = acc[r2][s][h];
                if (xo + 3 < W_OUT) {
                    *reinterpret_cast<float2*>(op)     = make_float2(v[0], v[1]);
                    *reinterpret_cast<float2*>(op + 2) = make_float2(v[2], v[3]);
                } else {
                    #pragma unroll
                    for (int qq = 0; qq < 4; ++qq)
                        if (xo + qq < W_OUT) op[qq] = v[qq];
                }
            }
        }
    }
}

extern "C" void kernel_launch(void* const* d_in, const int* in_sizes, int n_in,
                              void* d_out, int out_size, void* d_ws, size_t ws_size,
                              hipStream_t stream) {
    const float* x = (const float*)d_in[0];
    const float* w = (const float*)d_in[1];
    float* out     = (float*)d_out;

    const size_t XT_BYTES = (size_t)N_B * H_IN * W_IN * C_IN * 2;   // 67108864
    const size_t WT_BYTES = 9 * C_OUT * C_IN * 2;                   // 18432
    const size_t SLACK    = 131072;         // k2 staging over-reach (reads only)

    if (ws_size >= XT_BYTES + WT_BYTES + SLACK) {
        unsigned int*   xT = (unsigned int*)d_ws;
        unsigned short* wT = (unsigned short*)((char*)d_ws + XT_BYTES);
        hipLaunchKernelGGL(k1_tr,   dim3(N_B * H_IN + 1), dim3(256), 0, stream, x, xT, w, wT);
        hipLaunchKernelGGL(k2_conv, dim3(2048),           dim3(256), 0, stream,
                           (const unsigned short*)xT, wT, out);
    } else {
        hipLaunchKernelGGL(conv3x3_mfma, dim3(N_B * 128), dim3(256), 0, stream, x, w, out);
    }
}

// Round 11
// 57.270 us; speedup vs baseline: 6.8405x; 1.5829x over previous
//
#include <hip/hip_runtime.h>

// Fused 3x3 valid conv, fp32 NCHW in -> fp32 NCHW out, bf16 MFMA inside.
// x: (16,32,256,256) f32; w: (32,32,3,3) f32; out: (16,32,254,254) f32.
//
// Block = 512 thr (8 waves) = 128 out-px (half image width) x 16 out-rows x
// all 32 co. Input rows stream through a 4-slot LDS ring in [ci2][col] u32
// (bf16-pair) layout; staging is reg-based (2 coalesced float4 loads/wave/row
// + f2bf pair packing + one contiguous ds_write_b128).
// Sync: s_waitcnt lgkmcnt(0) + s_barrier ONLY (no vmcnt drain) -> global
// prefetch issued at step P is consumed at step P+2 (~2 steps of cover).
// R10 fix: stage ALL 9216 weight floats. R11 fix: restore STORE tail guard
// (xo=252 must write only px 252,253 -- unconditional 4-wide write clobbered
// the next row's cols 0-1 with zero-halo partial sums).

typedef __attribute__((ext_vector_type(8))) short bf16x8;
typedef __attribute__((ext_vector_type(4))) float f32x4;

#define MFMA(a,b,c) __builtin_amdgcn_mfma_f32_16x16x32_bf16((a),(b),(c),0,0,0)
#define SCHED0 __builtin_amdgcn_sched_barrier(0)
#define LGKMBAR asm volatile("s_waitcnt lgkmcnt(0)\n\ts_barrier" ::: "memory")

__device__ __forceinline__ unsigned short f2bf(float f) {
    unsigned int u = __float_as_uint(f);
    return (unsigned short)((u + 0x7FFFu + ((u >> 16) & 1u)) >> 16);   // RNE
}
__device__ __forceinline__ unsigned int packpair(float a, float b) {
    return (unsigned)f2bf(a) | ((unsigned)f2bf(b) << 16);  // lo=even ci, hi=odd ci
}

// LDS geometry: slot = 16 ci2-rows x 132 u32 cols (528 B row) = 8448 B; 4 slots.
// L sized for the weight stage (9216 f32 = 36864 B) >= ring (33792 B).
#define ROWW 132
#define SLOTW (16 * ROWW)

#define ROWCL(R_) ((R0 + (R_)) > 255 ? 255 : (R0 + (R_)))

// issue global loads for input row R (3-deep reg ring, literal %3)
#define ISSUE(R_) do {                                                       \
    const float* rp_ = xim + ((size_t)ROWCL(R_) << 8) + gpx;                 \
    gA[(R_) % 3] = *(const float4*)(rp_ + ((size_t)pA << 16));               \
    gB[(R_) % 3] = *(const float4*)(rp_ + (((size_t)pA + 1) << 16));         \
    if (h == 0 && wv == ((R_) & 7))                                          \
        gH[(R_) % 3] = *(const float2*)(xim + ((size_t)(lane >> 1) << 16)    \
                        + ((size_t)ROWCL(R_) << 8) + 128 + 2 * (lane & 1));  \
} while (0)

// convert + LDS-write input row R into slot R&3
#define CVTW(R_) do {                                                        \
    const float4 A_ = gA[(R_) % 3], B_ = gB[(R_) % 3];                       \
    unsigned int* d_ = &L[((R_) & 3) * SLOTW + (2 * wv + lhi) * ROWW + 4 * l31]; \
    *(uint4*)d_ = make_uint4(packpair(A_.x, B_.x), packpair(A_.y, B_.y),     \
                             packpair(A_.z, B_.z), packpair(A_.w, B_.w));    \
    if (h == 0 && wv == ((R_) & 7)) {                                        \
        const float2 V_ = gH[(R_) % 3];                                      \
        unsigned short* hp_ = (unsigned short*)&L[((R_) & 3) * SLOTW         \
                              + (lane >> 2) * ROWW + 128 + 2 * (lane & 1)]   \
                              + ((lane >> 1) & 1);                           \
        hp_[0] = f2bf(V_.x); hp_[2] = f2bf(V_.y);                            \
    }                                                                        \
} while (0)

#define MROW(P_, KY_) do {                                                   \
    if ((P_) - (KY_) >= 0 && (P_) - (KY_) <= 15) {                           \
        acc[(P_)-(KY_)][0] = MFMA(a0_.v, wf[(KY_)*3+0][0], acc[(P_)-(KY_)][0]); \
        acc[(P_)-(KY_)][0] = MFMA(a1_.v, wf[(KY_)*3+1][0], acc[(P_)-(KY_)][0]); \
        acc[(P_)-(KY_)][0] = MFMA(a2_.v, wf[(KY_)*3+2][0], acc[(P_)-(KY_)][0]); \
        acc[(P_)-(KY_)][1] = MFMA(a0_.v, wf[(KY_)*3+0][1], acc[(P_)-(KY_)][1]); \
        acc[(P_)-(KY_)][1] = MFMA(a1_.v, wf[(KY_)*3+1][1], acc[(P_)-(KY_)][1]); \
        acc[(P_)-(KY_)][1] = MFMA(a2_.v, wf[(KY_)*3+2][1], acc[(P_)-(KY_)][1]); \
    }                                                                        \
} while (0)

#define COMP(P_) do {                                                        \
    union { unsigned int u[4]; bf16x8 v; } a0_, a1_, a2_;                    \
    const unsigned int* sb_ = &L[((P_) & 3) * SLOTW + (g << 2) * ROWW        \
                                 + (wv << 4) + l15];                         \
    a0_.u[0] = sb_[0*ROWW+0]; a1_.u[0] = sb_[0*ROWW+1]; a2_.u[0] = sb_[0*ROWW+2]; \
    a0_.u[1] = sb_[1*ROWW+0]; a1_.u[1] = sb_[1*ROWW+1]; a2_.u[1] = sb_[1*ROWW+2]; \
    a0_.u[2] = sb_[2*ROWW+0]; a1_.u[2] = sb_[2*ROWW+1]; a2_.u[2] = sb_[2*ROWW+2]; \
    a0_.u[3] = sb_[3*ROWW+0]; a1_.u[3] = sb_[3*ROWW+1]; a2_.u[3] = sb_[3*ROWW+2]; \
    MROW(P_, 0); MROW(P_, 1); MROW(P_, 2);                                   \
} while (0)

#define STORE(R_) do {                                                       \
    if ((R_) >= 0 && (R_) <= 15) {                                           \
        const int y_ = R0 + (R_);                                            \
        if (y_ < 254) {                                                      \
            const int xo_ = (h << 7) + (wv << 4) + (g << 2);                 \
            _Pragma("unroll")                                                \
            for (int hh_ = 0; hh_ < 2; ++hh_) {                              \
                const f32x4 v_ = acc[R_][hh_];                               \
                float* p_ = out + (size_t)((n << 5) | (hh_ << 4) | l15) * 64516 \
                          + y_ * 254 + xo_;                                  \
                if (xo_ + 3 < 254) {                                         \
                    *(float2*)p_       = make_float2(v_[0], v_[1]);          \
                    *(float2*)(p_ + 2) = make_float2(v_[2], v_[3]);          \
                } else if (xo_ + 1 < 254) {        /* xo==252: px 252,253 */ \
                    *(float2*)p_ = make_float2(v_[0], v_[1]);                \
                }                                                            \
            }                                                                \
        }                                                                    \
    }                                                                        \
} while (0)

#define STEP(P_) do {                                                        \
    if ((P_) + 3 <= 17) ISSUE((P_) + 3);                                     \
    SCHED0;                                                                  \
    if ((P_) + 1 <= 17) CVTW((P_) + 1);                                      \
    LGKMBAR;                                                                 \
    COMP(P_);                                                                \
    STORE((P_) - 2);                                                         \
} while (0)

__global__ __launch_bounds__(512, 2)
void fconv(const float* __restrict__ x, const float* __restrict__ w,
           float* __restrict__ out) {
    __shared__ unsigned int L[9216];               // 36864 B (weights; ring uses 8448)

    const int tid  = threadIdx.x;
    const int bid  = blockIdx.x;
    const int o    = ((bid & 7) << 6) | (bid >> 3);   // XCD-chunked, bijective (512=8*64)
    const int n    = o >> 5;                          // image
    const int rb   = (o >> 1) & 15;                   // 16-row block
    const int h    = o & 1;                           // image half (128 px)
    const int wv   = tid >> 6;                        // wave 0..7 = 16-px strip
    const int lane = tid & 63;
    const int l15  = lane & 15;
    const int g    = lane >> 4;
    const int l31  = lane & 31;
    const int lhi  = lane >> 5;
    const int R0   = rb << 4;

    // ---- weights: stage ALL 9216 f32 -> LDS, then 18 reg B-frags
    #pragma unroll
    for (int k = 0; k < 18; ++k)
        ((float*)L)[tid + (k << 9)] = w[tid + (k << 9)];
    __syncthreads();
    bf16x8 wf[9][2];
    {
        const float* wl = (const float*)L;
        #pragma unroll
        for (int tap = 0; tap < 9; ++tap)
            #pragma unroll
            for (int hh = 0; hh < 2; ++hh) {
                union { unsigned short s[8]; bf16x8 v; } u;
                #pragma unroll
                for (int e = 0; e < 8; ++e)
                    u.s[e] = f2bf(wl[(hh * 16 + l15) * 288 + (8 * g + e) * 9 + tap]);
                wf[tap][hh] = u.v;
            }
    }
    __syncthreads();   // all frag reads done before L is reused as the ring

    // ---- h=1 never writes halo cols 128..131: zero them once (all 4 slots)
    if (h == 1 && tid < 256) {
        const int s_ = tid >> 6, r_ = (tid >> 2) & 15, c_ = tid & 3;
        L[s_ * SLOTW + r_ * ROWW + 128 + c_] = 0u;
    }

    const float* xim = x + ((size_t)n << 21);
    const int    pA  = 4 * wv + 2 * lhi;              // even plane of the lane's pair
    const int    gpx = (h << 7) + 4 * l31;            // global px of lane's float4

    float4 gA[3], gB[3];
    float2 gH[3];

    f32x4 acc[16][2];
    #pragma unroll
    for (int r = 0; r < 16; ++r)
        #pragma unroll
        for (int hh = 0; hh < 2; ++hh) {
            f32x4 z = {0.f, 0.f, 0.f, 0.f};
            acc[r][hh] = z;
        }

    // ---- prologue: 3 rows in flight, row 0 into LDS
    ISSUE(0); ISSUE(1); ISSUE(2);
    SCHED0;
    CVTW(0);
    LGKMBAR;   // seals zero-init + CVTW(0) before COMP(0)

    // ---- 18 steps (input rows R0..R0+17), fully unrolled
    STEP(0);  STEP(1);  STEP(2);  STEP(3);  STEP(4);  STEP(5);
    STEP(6);  STEP(7);  STEP(8);  STEP(9);  STEP(10); STEP(11);
    STEP(12); STEP(13); STEP(14); STEP(15); STEP(16); STEP(17);
}

extern "C" void kernel_launch(void* const* d_in, const int* in_sizes, int n_in,
                              void* d_out, int out_size, void* d_ws, size_t ws_size,
                              hipStream_t stream) {
    const float* x = (const float*)d_in[0];
    const float* w = (const float*)d_in[1];
    float* out     = (float*)d_out;
    hipLaunchKernelGGL(fconv, dim3(512), dim3(512), 0, stream, x, w, out);
}

// Round 12
// 56.875 us; speedup vs baseline: 6.8880x; 1.0070x over previous
//
#include <hip/hip_runtime.h>
#include <hip/hip_bf16.h>

// Fused 3x3 valid conv, fp32 NCHW in -> fp32 NCHW out, bf16 MFMA inside.
// x: (16,32,256,256) f32; w: (32,32,3,3) f32; out: (16,32,254,254) f32.
//
// Block = 512 thr (8 waves) = 128 out-px (half image width) x 16 out-rows x
// all 32 co. Input rows stream through a 4-slot LDS ring in [ci2][col] u32
// (bf16-pair) layout; staging is reg-based (2 coalesced float4 loads/wave/row
// + v_cvt_pk_bf16_f32 pairing + one contiguous ds_write_b128).
// Sync: s_waitcnt lgkmcnt(0) + s_barrier ONLY (no vmcnt drain) -> global
// prefetch issued at step P is consumed at step P+2 (~2 steps of cover).
// R12: packpair via __float22bfloat162_rn (1 VALU op vs ~9 bit-ops; same RNE).

typedef __attribute__((ext_vector_type(8))) short bf16x8;
typedef __attribute__((ext_vector_type(4))) float f32x4;

#define MFMA(a,b,c) __builtin_amdgcn_mfma_f32_16x16x32_bf16((a),(b),(c),0,0,0)
#define SCHED0 __builtin_amdgcn_sched_barrier(0)
#define LGKMBAR asm volatile("s_waitcnt lgkmcnt(0)\n\ts_barrier" ::: "memory")

__device__ __forceinline__ unsigned short f2bf(float f) {
    unsigned int u = __float_as_uint(f);
    return (unsigned short)((u + 0x7FFFu + ((u >> 16) & 1u)) >> 16);   // RNE
}
__device__ __forceinline__ unsigned int packpair(float a, float b) {
    __hip_bfloat162 t = __float22bfloat162_rn(make_float2(a, b));      // v_cvt_pk_bf16_f32
    union { __hip_bfloat162 h; unsigned int u; } c;                    // lo=a (even ci), hi=b
    c.h = t;
    return c.u;
}

// LDS geometry: slot = 16 ci2-rows x 132 u32 cols (528 B row) = 8448 B; 4 slots.
// L sized for the weight stage (9216 f32 = 36864 B) >= ring (33792 B).
#define ROWW 132
#define SLOTW (16 * ROWW)

#define ROWCL(R_) ((R0 + (R_)) > 255 ? 255 : (R0 + (R_)))

// issue global loads for input row R (3-deep reg ring, literal %3)
#define ISSUE(R_) do {                                                       \
    const float* rp_ = xim + ((size_t)ROWCL(R_) << 8) + gpx;                 \
    gA[(R_) % 3] = *(const float4*)(rp_ + ((size_t)pA << 16));               \
    gB[(R_) % 3] = *(const float4*)(rp_ + (((size_t)pA + 1) << 16));         \
    if (h == 0 && wv == ((R_) & 7))                                          \
        gH[(R_) % 3] = *(const float2*)(xim + ((size_t)(lane >> 1) << 16)    \
                        + ((size_t)ROWCL(R_) << 8) + 128 + 2 * (lane & 1));  \
} while (0)

// convert + LDS-write input row R into slot R&3
#define CVTW(R_) do {                                                        \
    const float4 A_ = gA[(R_) % 3], B_ = gB[(R_) % 3];                       \
    unsigned int* d_ = &L[((R_) & 3) * SLOTW + (2 * wv + lhi) * ROWW + 4 * l31]; \
    *(uint4*)d_ = make_uint4(packpair(A_.x, B_.x), packpair(A_.y, B_.y),     \
                             packpair(A_.z, B_.z), packpair(A_.w, B_.w));    \
    if (h == 0 && wv == ((R_) & 7)) {                                        \
        const float2 V_ = gH[(R_) % 3];                                      \
        unsigned short* hp_ = (unsigned short*)&L[((R_) & 3) * SLOTW         \
                              + (lane >> 2) * ROWW + 128 + 2 * (lane & 1)]   \
                              + ((lane >> 1) & 1);                           \
        hp_[0] = f2bf(V_.x); hp_[2] = f2bf(V_.y);                            \
    }                                                                        \
} while (0)

#define MROW(P_, KY_) do {                                                   \
    if ((P_) - (KY_) >= 0 && (P_) - (KY_) <= 15) {                           \
        acc[(P_)-(KY_)][0] = MFMA(a0_.v, wf[(KY_)*3+0][0], acc[(P_)-(KY_)][0]); \
        acc[(P_)-(KY_)][0] = MFMA(a1_.v, wf[(KY_)*3+1][0], acc[(P_)-(KY_)][0]); \
        acc[(P_)-(KY_)][0] = MFMA(a2_.v, wf[(KY_)*3+2][0], acc[(P_)-(KY_)][0]); \
        acc[(P_)-(KY_)][1] = MFMA(a0_.v, wf[(KY_)*3+0][1], acc[(P_)-(KY_)][1]); \
        acc[(P_)-(KY_)][1] = MFMA(a1_.v, wf[(KY_)*3+1][1], acc[(P_)-(KY_)][1]); \
        acc[(P_)-(KY_)][1] = MFMA(a2_.v, wf[(KY_)*3+2][1], acc[(P_)-(KY_)][1]); \
    }                                                                        \
} while (0)

#define COMP(P_) do {                                                        \
    union { unsigned int u[4]; bf16x8 v; } a0_, a1_, a2_;                    \
    const unsigned int* sb_ = &L[((P_) & 3) * SLOTW + (g << 2) * ROWW        \
                                 + (wv << 4) + l15];                         \
    a0_.u[0] = sb_[0*ROWW+0]; a1_.u[0] = sb_[0*ROWW+1]; a2_.u[0] = sb_[0*ROWW+2]; \
    a0_.u[1] = sb_[1*ROWW+0]; a1_.u[1] = sb_[1*ROWW+1]; a2_.u[1] = sb_[1*ROWW+2]; \
    a0_.u[2] = sb_[2*ROWW+0]; a1_.u[2] = sb_[2*ROWW+1]; a2_.u[2] = sb_[2*ROWW+2]; \
    a0_.u[3] = sb_[3*ROWW+0]; a1_.u[3] = sb_[3*ROWW+1]; a2_.u[3] = sb_[3*ROWW+2]; \
    MROW(P_, 0); MROW(P_, 1); MROW(P_, 2);                                   \
} while (0)

#define STORE(R_) do {                                                       \
    if ((R_) >= 0 && (R_) <= 15) {                                           \
        const int y_ = R0 + (R_);                                            \
        if (y_ < 254) {                                                      \
            const int xo_ = (h << 7) + (wv << 4) + (g << 2);                 \
            _Pragma("unroll")                                                \
            for (int hh_ = 0; hh_ < 2; ++hh_) {                              \
                const f32x4 v_ = acc[R_][hh_];                               \
                float* p_ = out + (size_t)((n << 5) | (hh_ << 4) | l15) * 64516 \
                          + y_ * 254 + xo_;                                  \
                if (xo_ + 3 < 254) {                                         \
                    *(float2*)p_       = make_float2(v_[0], v_[1]);          \
                    *(float2*)(p_ + 2) = make_float2(v_[2], v_[3]);          \
                } else if (xo_ + 1 < 254) {        /* xo==252: px 252,253 */ \
                    *(float2*)p_ = make_float2(v_[0], v_[1]);                \
                }                                                            \
            }                                                                \
        }                                                                    \
    }                                                                        \
} while (0)

#define STEP(P_) do {                                                        \
    if ((P_) + 3 <= 17) ISSUE((P_) + 3);                                     \
    SCHED0;                                                                  \
    if ((P_) + 1 <= 17) CVTW((P_) + 1);                                      \
    LGKMBAR;                                                                 \
    COMP(P_);                                                                \
    STORE((P_) - 2);                                                         \
} while (0)

__global__ __launch_bounds__(512, 2)
void fconv(const float* __restrict__ x, const float* __restrict__ w,
           float* __restrict__ out) {
    __shared__ unsigned int L[9216];               // 36864 B (weights; ring uses 8448)

    const int tid  = threadIdx.x;
    const int bid  = blockIdx.x;
    const int o    = ((bid & 7) << 6) | (bid >> 3);   // XCD-chunked, bijective (512=8*64)
    const int n    = o >> 5;                          // image
    const int rb   = (o >> 1) & 15;                   // 16-row block
    const int h    = o & 1;                           // image half (128 px)
    const int wv   = tid >> 6;                        // wave 0..7 = 16-px strip
    const int lane = tid & 63;
    const int l15  = lane & 15;
    const int g    = lane >> 4;
    const int l31  = lane & 31;
    const int lhi  = lane >> 5;
    const int R0   = rb << 4;

    // ---- weights: stage ALL 9216 f32 -> LDS, then 18 reg B-frags
    #pragma unroll
    for (int k = 0; k < 18; ++k)
        ((float*)L)[tid + (k << 9)] = w[tid + (k << 9)];
    __syncthreads();
    bf16x8 wf[9][2];
    {
        const float* wl = (const float*)L;
        #pragma unroll
        for (int tap = 0; tap < 9; ++tap)
            #pragma unroll
            for (int hh = 0; hh < 2; ++hh) {
                union { unsigned short s[8]; bf16x8 v; } u;
                #pragma unroll
                for (int e = 0; e < 8; ++e)
                    u.s[e] = f2bf(wl[(hh * 16 + l15) * 288 + (8 * g + e) * 9 + tap]);
                wf[tap][hh] = u.v;
            }
    }
    __syncthreads();   // all frag reads done before L is reused as the ring

    // ---- h=1 never writes halo cols 128..131: zero them once (all 4 slots)
    if (h == 1 && tid < 256) {
        const int s_ = tid >> 6, r_ = (tid >> 2) & 15, c_ = tid & 3;
        L[s_ * SLOTW + r_ * ROWW + 128 + c_] = 0u;
    }

    const float* xim = x + ((size_t)n << 21);
    const int    pA  = 4 * wv + 2 * lhi;              // even plane of the lane's pair
    const int    gpx = (h << 7) + 4 * l31;            // global px of lane's float4

    float4 gA[3], gB[3];
    float2 gH[3];

    f32x4 acc[16][2];
    #pragma unroll
    for (int r = 0; r < 16; ++r)
        #pragma unroll
        for (int hh = 0; hh < 2; ++hh) {
            f32x4 z = {0.f, 0.f, 0.f, 0.f};
            acc[r][hh] = z;
        }

    // ---- prologue: 3 rows in flight, row 0 into LDS
    ISSUE(0); ISSUE(1); ISSUE(2);
    SCHED0;
    CVTW(0);
    LGKMBAR;   // seals zero-init + CVTW(0) before COMP(0)

    // ---- 18 steps (input rows R0..R0+17), fully unrolled
    STEP(0);  STEP(1);  STEP(2);  STEP(3);  STEP(4);  STEP(5);
    STEP(6);  STEP(7);  STEP(8);  STEP(9);  STEP(10); STEP(11);
    STEP(12); STEP(13); STEP(14); STEP(15); STEP(16); STEP(17);
}

extern "C" void kernel_launch(void* const* d_in, const int* in_sizes, int n_in,
                              void* d_out, int out_size, void* d_ws, size_t ws_size,
                              hipStream_t stream) {
    const float* x = (const float*)d_in[0];
    const float* w = (const float*)d_in[1];
    float* out     = (float*)d_out;
    hipLaunchKernelGGL(fconv, dim3(512), dim3(512), 0, stream, x, w, out);
}

// Round 13
// 56.030 us; speedup vs baseline: 6.9919x; 1.0151x over previous
//
#include <hip/hip_runtime.h>
#include <hip/hip_bf16.h>

// Fused 3x3 valid conv, fp32 NCHW in -> fp32 NCHW out, bf16 MFMA inside.
// x: (16,32,256,256) f32; w: (32,32,3,3) f32; out: (16,32,254,254) f32.
//
// Block = 512 thr (8 waves) = 128 out-px (half image width) x 16 out-rows x
// all 32 co. R13: TWO input rows per step -> 9 lgkm-barriers instead of 18.
// 8-slot LDS ring (race-required: leader writes slots (P+2/P+3)&7 while a
// post-barrier laggard still reads (P-2/P-1)&7 -- disjoint only mod 8).
// CVTW before ISSUE keeps the gA/gB/gH register rings 3-deep.

typedef __attribute__((ext_vector_type(8))) short bf16x8;
typedef __attribute__((ext_vector_type(4))) float f32x4;

#define MFMA(a,b,c) __builtin_amdgcn_mfma_f32_16x16x32_bf16((a),(b),(c),0,0,0)
#define SCHED0 __builtin_amdgcn_sched_barrier(0)
#define LGKMBAR asm volatile("s_waitcnt lgkmcnt(0)\n\ts_barrier" ::: "memory")

__device__ __forceinline__ unsigned short f2bf(float f) {
    unsigned int u = __float_as_uint(f);
    return (unsigned short)((u + 0x7FFFu + ((u >> 16) & 1u)) >> 16);   // RNE
}
__device__ __forceinline__ unsigned int packpair(float a, float b) {
    __hip_bfloat162 t = __float22bfloat162_rn(make_float2(a, b));      // v_cvt_pk_bf16_f32
    union { __hip_bfloat162 h; unsigned int u; } c;                    // lo=a (even ci), hi=b
    c.h = t;
    return c.u;
}

// LDS: slot = 16 ci2-rows x 132 u32 (528 B row) = 8448 B; 8 slots = 67584 B.
#define ROWW 132
#define SLOTW (16 * ROWW)

#define ROWCL(R_) ((R0 + (R_)) > 255 ? 255 : (R0 + (R_)))

// issue global loads for input row R (3-deep reg ring, literal %3)
#define ISSUE(R_) do {                                                       \
    const float* rp_ = xim + ((size_t)ROWCL(R_) << 8) + gpx;                 \
    gA[(R_) % 3] = *(const float4*)(rp_ + ((size_t)pA << 16));               \
    gB[(R_) % 3] = *(const float4*)(rp_ + (((size_t)pA + 1) << 16));         \
    if (h == 0 && wv == ((R_) & 7))                                          \
        gH[(R_) % 3] = *(const float2*)(xim + ((size_t)(lane >> 1) << 16)    \
                        + ((size_t)ROWCL(R_) << 8) + 128 + 2 * (lane & 1));  \
} while (0)

// convert + LDS-write input row R into slot R&7
#define CVTW(R_) do {                                                        \
    const float4 A_ = gA[(R_) % 3], B_ = gB[(R_) % 3];                       \
    unsigned int* d_ = &L[((R_) & 7) * SLOTW + (2 * wv + lhi) * ROWW + 4 * l31]; \
    *(uint4*)d_ = make_uint4(packpair(A_.x, B_.x), packpair(A_.y, B_.y),     \
                             packpair(A_.z, B_.z), packpair(A_.w, B_.w));    \
    if (h == 0 && wv == ((R_) & 7)) {                                        \
        const float2 V_ = gH[(R_) % 3];                                      \
        unsigned short* hp_ = (unsigned short*)&L[((R_) & 7) * SLOTW         \
                              + (lane >> 2) * ROWW + 128 + 2 * (lane & 1)]   \
                              + ((lane >> 1) & 1);                           \
        hp_[0] = f2bf(V_.x); hp_[2] = f2bf(V_.y);                            \
    }                                                                        \
} while (0)

#define MROW(P_, KY_) do {                                                   \
    if ((P_) - (KY_) >= 0 && (P_) - (KY_) <= 15) {                           \
        acc[(P_)-(KY_)][0] = MFMA(a0_.v, wf[(KY_)*3+0][0], acc[(P_)-(KY_)][0]); \
        acc[(P_)-(KY_)][0] = MFMA(a1_.v, wf[(KY_)*3+1][0], acc[(P_)-(KY_)][0]); \
        acc[(P_)-(KY_)][0] = MFMA(a2_.v, wf[(KY_)*3+2][0], acc[(P_)-(KY_)][0]); \
        acc[(P_)-(KY_)][1] = MFMA(a0_.v, wf[(KY_)*3+0][1], acc[(P_)-(KY_)][1]); \
        acc[(P_)-(KY_)][1] = MFMA(a1_.v, wf[(KY_)*3+1][1], acc[(P_)-(KY_)][1]); \
        acc[(P_)-(KY_)][1] = MFMA(a2_.v, wf[(KY_)*3+2][1], acc[(P_)-(KY_)][1]); \
    }                                                                        \
} while (0)

#define COMP(P_) do {                                                        \
    union { unsigned int u[4]; bf16x8 v; } a0_, a1_, a2_;                    \
    const unsigned int* sb_ = &L[((P_) & 7) * SLOTW + (g << 2) * ROWW        \
                                 + (wv << 4) + l15];                         \
    a0_.u[0] = sb_[0*ROWW+0]; a1_.u[0] = sb_[0*ROWW+1]; a2_.u[0] = sb_[0*ROWW+2]; \
    a0_.u[1] = sb_[1*ROWW+0]; a1_.u[1] = sb_[1*ROWW+1]; a2_.u[1] = sb_[1*ROWW+2]; \
    a0_.u[2] = sb_[2*ROWW+0]; a1_.u[2] = sb_[2*ROWW+1]; a2_.u[2] = sb_[2*ROWW+2]; \
    a0_.u[3] = sb_[3*ROWW+0]; a1_.u[3] = sb_[3*ROWW+1]; a2_.u[3] = sb_[3*ROWW+2]; \
    MROW(P_, 0); MROW(P_, 1); MROW(P_, 2);                                   \
} while (0)

#define STORE(R_) do {                                                       \
    if ((R_) >= 0 && (R_) <= 15) {                                           \
        const int y_ = R0 + (R_);                                            \
        if (y_ < 254) {                                                      \
            const int xo_ = (h << 7) + (wv << 4) + (g << 2);                 \
            _Pragma("unroll")                                                \
            for (int hh_ = 0; hh_ < 2; ++hh_) {                              \
                const f32x4 v_ = acc[R_][hh_];                               \
                float* p_ = out + (size_t)((n << 5) | (hh_ << 4) | l15) * 64516 \
                          + y_ * 254 + xo_;                                  \
                if (xo_ + 3 < 254) {                                         \
                    *(float2*)p_       = make_float2(v_[0], v_[1]);          \
                    *(float2*)(p_ + 2) = make_float2(v_[2], v_[3]);          \
                } else if (xo_ + 1 < 254) {        /* xo==252: px 252,253 */ \
                    *(float2*)p_ = make_float2(v_[0], v_[1]);                \
                }                                                            \
            }                                                                \
        }                                                                    \
    }                                                                        \
} while (0)

// Two-row step (P even). CVTW first (keeps reg rings 3-deep), then ISSUE,
// one lgkm barrier, two COMPs, two STOREs.
#define STEP2(P_) do {                                                       \
    if ((P_) + 2 <= 17) CVTW((P_) + 2);                                      \
    if ((P_) + 3 <= 17) CVTW((P_) + 3);                                      \
    SCHED0;                                                                  \
    if ((P_) + 4 <= 17) ISSUE((P_) + 4);                                     \
    if ((P_) + 5 <= 17) ISSUE((P_) + 5);                                     \
    LGKMBAR;                                                                 \
    COMP(P_);                                                                \
    COMP((P_) + 1);                                                          \
    STORE((P_) - 2);                                                         \
    STORE((P_) - 1);                                                         \
} while (0)

__global__ __launch_bounds__(512, 2)
void fconv(const float* __restrict__ x, const float* __restrict__ w,
           float* __restrict__ out) {
    __shared__ unsigned int L[8 * SLOTW];          // 67584 B (weights use 36864)

    const int tid  = threadIdx.x;
    const int bid  = blockIdx.x;
    const int o    = ((bid & 7) << 6) | (bid >> 3);   // XCD-chunked, bijective (512=8*64)
    const int n    = o >> 5;                          // image
    const int rb   = (o >> 1) & 15;                   // 16-row block
    const int h    = o & 1;                           // image half (128 px)
    const int wv   = tid >> 6;                        // wave 0..7 = 16-px strip
    const int lane = tid & 63;
    const int l15  = lane & 15;
    const int g    = lane >> 4;
    const int l31  = lane & 31;
    const int lhi  = lane >> 5;
    const int R0   = rb << 4;

    // ---- weights: stage ALL 9216 f32 -> LDS, then 18 reg B-frags
    #pragma unroll
    for (int k = 0; k < 18; ++k)
        ((float*)L)[tid + (k << 9)] = w[tid + (k << 9)];
    __syncthreads();
    bf16x8 wf[9][2];
    {
        const float* wl = (const float*)L;
        #pragma unroll
        for (int tap = 0; tap < 9; ++tap)
            #pragma unroll
            for (int hh = 0; hh < 2; ++hh) {
                union { unsigned short s[8]; bf16x8 v; } u;
                #pragma unroll
                for (int e = 0; e < 8; ++e)
                    u.s[e] = f2bf(wl[(hh * 16 + l15) * 288 + (8 * g + e) * 9 + tap]);
                wf[tap][hh] = u.v;
            }
    }
    __syncthreads();   // all frag reads done before L is reused as the ring

    // ---- h=1 never writes halo cols 128..131: zero them once (all 8 slots)
    if (h == 1) {
        const int s_ = tid >> 6, r_ = (tid >> 2) & 15, c_ = tid & 3;
        L[s_ * SLOTW + r_ * ROWW + 128 + c_] = 0u;   // 512 thr = 8x16x4 exactly
    }

    const float* xim = x + ((size_t)n << 21);
    const int    pA  = 4 * wv + 2 * lhi;              // even plane of the lane's pair
    const int    gpx = (h << 7) + 4 * l31;            // global px of lane's float4

    float4 gA[3], gB[3];
    float2 gH[3];

    f32x4 acc[16][2];
    #pragma unroll
    for (int r = 0; r < 16; ++r)
        #pragma unroll
        for (int hh = 0; hh < 2; ++hh) {
            f32x4 z = {0.f, 0.f, 0.f, 0.f};
            acc[r][hh] = z;
        }

    // ---- prologue: rows 0..2 issued; rows 0,1 into LDS; row 3 issued late
    ISSUE(0); ISSUE(1); ISSUE(2);
    SCHED0;
    CVTW(0); CVTW(1);
    ISSUE(3);                       // gA[0] reused after CVTW(0) consumed it
    LGKMBAR;                        // seals zero-init + CVTW(0,1) before COMP(0,1)

    // ---- 9 two-row steps (input rows R0..R0+17), fully unrolled
    STEP2(0);  STEP2(2);  STEP2(4);  STEP2(6);  STEP2(8);
    STEP2(10); STEP2(12); STEP2(14); STEP2(16);
}

extern "C" void kernel_launch(void* const* d_in, const int* in_sizes, int n_in,
                              void* d_out, int out_size, void* d_ws, size_t ws_size,
                              hipStream_t stream) {
    const float* x = (const float*)d_in[0];
    const float* w = (const float*)d_in[1];
    float* out     = (float*)d_out;
    hipLaunchKernelGGL(fconv, dim3(512), dim3(512), 0, stream, x, w, out);
}